// Round 5
// baseline (518.778 us; speedup 1.0000x reference)
//
#include <hip/hip_runtime.h>
#include <hip/hip_bf16.h>
#include <math.h>

#define NN 100000
#define EE 1600000
#define DD 256
#define DEE 8
#define HF 128           // H*F
#define NEG_SLOPE 0.2f
#define NBUCK 196        // ceil(NN/512) coarse dst-buckets (512 nodes each)
#define P1_EPB 2048      // edges per block in bucket_scatter (782 blocks)
#define P1_TPB 512       // threads per block (8 waves -> ~24 waves/CU)
#define P1_ITER (P1_EPB / P1_TPB)   // 4

typedef __bf16 bf16x8 __attribute__((ext_vector_type(8)));
typedef float  f32x4  __attribute__((ext_vector_type(4)));

__device__ inline ushort f2bf(float f) {          // round-to-nearest-even
    uint32_t x = __builtin_bit_cast(uint32_t, f);
    x += 0x7fffu + ((x >> 16) & 1u);
    return (ushort)(x >> 16);
}
__device__ inline float bf2f(ushort u) {
    uint32_t x = ((uint32_t)u) << 16;
    return __builtin_bit_cast(float, x);
}
__device__ inline float u2f(uint u) { return __builtin_bit_cast(float, u); }
__device__ inline uint f2u(float f) { return __builtin_bit_cast(uint, f); }
__device__ inline float lo_bf(uint p) { return __builtin_bit_cast(float, p << 16); }
__device__ inline float hi_bf(uint p) { return __builtin_bit_cast(float, p & 0xffff0000u); }

__device__ inline void load_lds16(const void* g, void* l) {
    __builtin_amdgcn_global_load_lds(
        (const __attribute__((address_space(1))) void*)g,
        (__attribute__((address_space(3))) void*)l, 16, 0, 0);
}

// ---------------------------------------------------------------------------
// fp32 -> bf16 for the 3 weight matrices in one launch
// ---------------------------------------------------------------------------
__global__ __launch_bounds__(256) void f2bf3_kernel(
    const float* __restrict__ wa, const float* __restrict__ wb,
    const float* __restrict__ wc,
    ushort* __restrict__ oa, ushort* __restrict__ ob, ushort* __restrict__ oc)
{
    int i = (blockIdx.x * 256 + threadIdx.x) * 4;
    const int na = HF * DD, nb2 = 2 * HF * DD, nc3 = 2 * HF * DD + HF * HF;
    const float* src; ushort* dst; int o;
    if (i < na)       { src = wa; dst = oa; o = i; }
    else if (i < nb2) { src = wb; dst = ob; o = i - na; }
    else if (i < nc3) { src = wc; dst = oc; o = i - nb2; }
    else return;
    float4 v = *(const float4*)(src + o);
    ushort4 u;
    u.x = f2bf(v.x); u.y = f2bf(v.y); u.z = f2bf(v.z); u.w = f2bf(v.w);
    *(ushort4*)(dst + o) = u;
}

// ---------------------------------------------------------------------------
// FUSED: attn logits + dual projection GEMM. One 64-node tile per block.
// Phase A: stage full-K B-tile (fp32 feat -> bf16 LDS, reg path) and, while
//          the fp32 octet is live in registers, accumulate the 4 attention
//          logit dots (fp32 precision preserved). Kills the feat_bf
//          round-trip (102.4 MB HBM) and the separate attn kernel.
// Phase B: MFMA K-loop (A slabs staged per step; B already resident).
// ---------------------------------------------------------------------------
template<int K>
__global__ __launch_bounds__(256) void gemm_dual_attn(
    const ushort* __restrict__ W0,     // [128][K] bf16
    const ushort* __restrict__ W1,     // [128][K] bf16
    const float*  __restrict__ Xf,     // [NN][K] fp32 feat
    const float*  __restrict__ Was,    // [2][K] fp32
    const float*  __restrict__ Wad,    // [2][K] fp32
    const float*  __restrict__ bias1,  // [128]
    float* __restrict__ a_src, float* __restrict__ a_dst,
    ushort* __restrict__ out0, ushort* __restrict__ out1)
{
    __shared__ ushort As[2][128 * 32];   // 16 KB, per-step W slabs
    __shared__ ushort Bsf[8][64 * 32];   // 32 KB, full-K B tile
    __shared__ float  wlds[4][K];        // 4 KB, attn vectors

    const int tid  = threadIdx.x;
    const int lane = tid & 63, wv = tid >> 6;
    const int wm = wv >> 1, wn = wv & 1;
    const int r = lane & 15, quad = lane >> 4;
    const int m0 = blockIdx.x * 64;

    // preload attn vectors: 4 x K floats, 1 float4 per thread
    {
        int vec = tid >> 6, e = (tid & 63) * 4;
        const float* src = (vec < 2) ? (Was + vec * K + e) : (Wad + (vec - 2) * K + e);
        *(float4*)&wlds[vec][e] = *(const float4*)src;
    }
    __syncthreads();

    // Phase A: stage B + logits. thread -> (node = tid>>2, k-octet = (tid&3)*8)
    const int node = tid >> 2;
    const int kq   = (tid & 3) * 8;
    int gm = m0 + node; gm = gm < NN ? gm : NN - 1;
    const float* frow = Xf + (size_t)gm * K;
    float p0 = 0.f, p1 = 0.f, p2 = 0.f, p3 = 0.f;
#pragma unroll
    for (int st = 0; st < 8; ++st) {
        int k = st * 32 + kq;
        float4 fa = *(const float4*)(frow + k);
        float4 fb = *(const float4*)(frow + k + 4);
        uint q0 = ((uint)f2bf(fa.y) << 16) | f2bf(fa.x);
        uint q1 = ((uint)f2bf(fa.w) << 16) | f2bf(fa.z);
        uint q2 = ((uint)f2bf(fb.y) << 16) | f2bf(fb.x);
        uint q3 = ((uint)f2bf(fb.w) << 16) | f2bf(fb.z);
        *(uint4*)&Bsf[st][node * 32 + kq] = make_uint4(q0, q1, q2, q3);

        float4 wv0a = *(const float4*)&wlds[0][k];
        float4 wv0b = *(const float4*)&wlds[0][k + 4];
        float4 wv1a = *(const float4*)&wlds[1][k];
        float4 wv1b = *(const float4*)&wlds[1][k + 4];
        float4 wv2a = *(const float4*)&wlds[2][k];
        float4 wv2b = *(const float4*)&wlds[2][k + 4];
        float4 wv3a = *(const float4*)&wlds[3][k];
        float4 wv3b = *(const float4*)&wlds[3][k + 4];
        p0 += fa.x*wv0a.x + fa.y*wv0a.y + fa.z*wv0a.z + fa.w*wv0a.w
            + fb.x*wv0b.x + fb.y*wv0b.y + fb.z*wv0b.z + fb.w*wv0b.w;
        p1 += fa.x*wv1a.x + fa.y*wv1a.y + fa.z*wv1a.z + fa.w*wv1a.w
            + fb.x*wv1b.x + fb.y*wv1b.y + fb.z*wv1b.z + fb.w*wv1b.w;
        p2 += fa.x*wv2a.x + fa.y*wv2a.y + fa.z*wv2a.z + fa.w*wv2a.w
            + fb.x*wv2b.x + fb.y*wv2b.y + fb.z*wv2b.z + fb.w*wv2b.w;
        p3 += fa.x*wv3a.x + fa.y*wv3a.y + fa.z*wv3a.z + fa.w*wv3a.w
            + fb.x*wv3b.x + fb.y*wv3b.y + fb.z*wv3b.z + fb.w*wv3b.w;
    }
    // fold the 4 k-octet threads of each node (lanes differ in low 2 bits)
    p0 += __shfl_xor(p0, 1); p0 += __shfl_xor(p0, 2);
    p1 += __shfl_xor(p1, 1); p1 += __shfl_xor(p1, 2);
    p2 += __shfl_xor(p2, 1); p2 += __shfl_xor(p2, 2);
    p3 += __shfl_xor(p3, 1); p3 += __shfl_xor(p3, 2);
    if ((tid & 3) == 0 && m0 + node < NN) {
        *(float2*)&a_src[(size_t)(m0 + node) * 2] = make_float2(p0, p1);
        *(float2*)&a_dst[(size_t)(m0 + node) * 2] = make_float2(p2, p3);
    }
    __syncthreads();

    // Phase B: MFMA K-loop
    f32x4 acc[2][4][2] = {};
    for (int k0 = 0; k0 < K; k0 += 32) {
#pragma unroll
        for (int t = 0; t < 2; ++t) {
            int is  = wv + t * 4;
            int row = is * 16 + (lane >> 2);
            int ko  = k0 + (lane & 3) * 8;
            load_lds16(W0 + (size_t)row * K + ko, &As[0][is * 512]);
            load_lds16(W1 + (size_t)row * K + ko, &As[1][is * 512]);
        }
        __syncthreads();
        bf16x8 a[2][4], b[2];
#pragma unroll
        for (int i = 0; i < 4; ++i) {
            a[0][i] = __builtin_bit_cast(bf16x8,
                      *(const f32x4*)&As[0][(wm * 64 + i * 16 + r) * 32 + quad * 8]);
            a[1][i] = __builtin_bit_cast(bf16x8,
                      *(const f32x4*)&As[1][(wm * 64 + i * 16 + r) * 32 + quad * 8]);
        }
#pragma unroll
        for (int j = 0; j < 2; ++j)
            b[j] = __builtin_bit_cast(bf16x8,
                   *(const f32x4*)&Bsf[k0 >> 5][(wn * 32 + j * 16 + r) * 32 + quad * 8]);
#pragma unroll
        for (int s = 0; s < 2; ++s)
#pragma unroll
            for (int i = 0; i < 4; ++i)
#pragma unroll
                for (int j = 0; j < 2; ++j)
                    acc[s][i][j] = __builtin_amdgcn_mfma_f32_16x16x32_bf16(
                        a[s][i], b[j], acc[s][i][j], 0, 0, 0);
        __syncthreads();
    }

#pragma unroll
    for (int s = 0; s < 2; ++s) {
        ushort* outp = s ? out1 : out0;
#pragma unroll
        for (int i = 0; i < 4; ++i) {
            int fbase = wm * 64 + i * 16 + quad * 4;
            float4 bv = make_float4(0.f, 0.f, 0.f, 0.f);
            if (s == 1) bv = *(const float4*)(bias1 + fbase);
#pragma unroll
            for (int j = 0; j < 2; ++j) {
                int node2 = m0 + wn * 32 + j * 16 + r;
                if (node2 >= NN) continue;
                f32x4 v = acc[s][i][j];
                v[0] += bv.x; v[1] += bv.y; v[2] += bv.z; v[3] += bv.w;
                ushort4 o;
                o.x = f2bf(v[0]); o.y = f2bf(v[1]); o.z = f2bf(v[2]); o.w = f2bf(v[3]);
                *(ushort4*)(outp + (size_t)node2 * HF + fbase) = o;
            }
        }
    }
}

// ---------------------------------------------------------------------------
// ngnn GEMM (K=128): fp32 out[node][f] = relu(acc+bias) + bf2f(resid)
// ---------------------------------------------------------------------------
template<int K>
__global__ __launch_bounds__(256) void mfma_gemm_ngnn(
    const ushort* __restrict__ Wb,
    const ushort* __restrict__ Xb,
    const float*  __restrict__ bias,
    const ushort* __restrict__ resid,
    float* __restrict__ outp)
{
    __shared__ ushort As[128 * 32];
    __shared__ ushort Bs[128 * 32];

    const int tid  = threadIdx.x;
    const int lane = tid & 63, wv = tid >> 6;
    const int wm = wv >> 1, wn = wv & 1;
    const int r = lane & 15, quad = lane >> 4;
    const int m0 = blockIdx.x * 128;

    f32x4 acc[4][4] = {};

    for (int k0 = 0; k0 < K; k0 += 32) {
#pragma unroll
        for (int t = 0; t < 2; ++t) {
            int is  = wv + t * 4;
            int row = is * 16 + (lane >> 2);
            int ko  = k0 + (lane & 3) * 8;
            load_lds16(Wb + (size_t)row * K + ko, &As[is * 512]);
            int gm = m0 + row; gm = gm < NN ? gm : NN - 1;
            load_lds16(Xb + (size_t)gm * K + ko, &Bs[is * 512]);
        }
        __syncthreads();
        bf16x8 a[4], b[4];
#pragma unroll
        for (int i = 0; i < 4; ++i) {
            a[i] = __builtin_bit_cast(bf16x8,
                   *(const f32x4*)&As[(wm * 64 + i * 16 + r) * 32 + quad * 8]);
            b[i] = __builtin_bit_cast(bf16x8,
                   *(const f32x4*)&Bs[(wn * 64 + i * 16 + r) * 32 + quad * 8]);
        }
#pragma unroll
        for (int i = 0; i < 4; ++i)
#pragma unroll
            for (int j = 0; j < 4; ++j)
                acc[i][j] = __builtin_amdgcn_mfma_f32_16x16x32_bf16(
                    a[i], b[j], acc[i][j], 0, 0, 0);
        __syncthreads();
    }

#pragma unroll
    for (int i = 0; i < 4; ++i) {
        int fbase = wm * 64 + i * 16 + quad * 4;
        float4 bv = *(const float4*)(bias + fbase);
#pragma unroll
        for (int j = 0; j < 4; ++j) {
            int node = m0 + wn * 64 + j * 16 + r;
            if (node >= NN) continue;
            f32x4 v = acc[i][j];
            ushort4 rs = *(const ushort4*)(resid + (size_t)node * HF + fbase);
            float4 o;
            o.x = fmaxf(v[0] + bv.x, 0.f) + bf2f(rs.x);
            o.y = fmaxf(v[1] + bv.y, 0.f) + bf2f(rs.y);
            o.z = fmaxf(v[2] + bv.z, 0.f) + bf2f(rs.z);
            o.w = fmaxf(v[3] + bv.w, 0.f) + bf2f(rs.w);
            *(float4*)(outp + (size_t)node * HF + fbase) = o;
        }
    }
}

// ---------------------------------------------------------------------------
// CSR degree histogram + scan
// ---------------------------------------------------------------------------
__global__ __launch_bounds__(256) void hist_kernel(
    const int* __restrict__ edge_dst, int* __restrict__ deg)
{
    int i = blockIdx.x * 256 + threadIdx.x;
    if (i < EE) atomicAdd(&deg[edge_dst[i]], 1);
}

#define SCAN_ELEMS 1024
__global__ __launch_bounds__(256) void scan1_kernel(
    const int* __restrict__ deg, int* __restrict__ offsets, int* __restrict__ blockSums)
{
    __shared__ int sd[256];
    int tid = threadIdx.x;
    int base = blockIdx.x * SCAN_ELEMS + tid * 4;
    int v[4];
#pragma unroll
    for (int c = 0; c < 4; ++c) v[c] = (base + c < NN) ? deg[base + c] : 0;
    int tsum = v[0] + v[1] + v[2] + v[3];
    sd[tid] = tsum;
    __syncthreads();
    for (int o = 1; o < 256; o <<= 1) {
        int x = (tid >= o) ? sd[tid - o] : 0;
        __syncthreads();
        sd[tid] += x;
        __syncthreads();
    }
    int excl = sd[tid] - tsum;
    int run = excl;
#pragma unroll
    for (int c = 0; c < 4; ++c) {
        if (base + c < NN) offsets[base + c] = run;
        run += v[c];
    }
    if (tid == 255) blockSums[blockIdx.x] = sd[255];
}

__global__ __launch_bounds__(128) void scan2_kernel(int* __restrict__ blockSums, int nb)
{
    __shared__ int sd[128];
    int tid = threadIdx.x;
    int tv = (tid < nb) ? blockSums[tid] : 0;
    sd[tid] = tv;
    __syncthreads();
    for (int o = 1; o < 128; o <<= 1) {
        int x = (tid >= o) ? sd[tid - o] : 0;
        __syncthreads();
        sd[tid] += x;
        __syncthreads();
    }
    if (tid < nb) blockSums[tid] = sd[tid] - tv;
}

// scan3 + bucket-cursor init fused
__global__ __launch_bounds__(256) void scan3_kernel(
    int* __restrict__ offsets, const int* __restrict__ blockSums,
    int* __restrict__ bcur)
{
    int tid = threadIdx.x;
    int base = blockIdx.x * SCAN_ELEMS + tid * 4;
    int add = blockSums[blockIdx.x];
#pragma unroll
    for (int c = 0; c < 4; ++c) {
        int idx = base + c;
        if (idx < NN) {
            int v = offsets[idx] + add;
            offsets[idx] = v;
            if ((idx & 511) == 0) bcur[idx >> 9] = v;
        }
    }
    if (blockIdx.x == 0 && tid == 0) offsets[NN] = EE;
}

// ---------------------------------------------------------------------------
// Phase 1: fused edge-score + coarse bucket scatter.
// ---------------------------------------------------------------------------
__global__ __launch_bounds__(P1_TPB) void bucket_scatter_kernel(
    const int* __restrict__ edge_src, const int* __restrict__ edge_dst,
    const float* __restrict__ feat_edge,
    const float* __restrict__ a_src, const float* __restrict__ a_dst,
    const float* __restrict__ Wae,
    int* __restrict__ bcur, uint4* __restrict__ staging)
{
    __shared__ uint4 rec[P1_EPB];      // 32 KB in-block sorted records
    __shared__ int cnt[256];
    __shared__ int scanv[256];         // exclusive bucket start within block
    __shared__ int cur[256];           // running cursor for LDS scatter
    __shared__ int basearr[256];       // global base per bucket
    __shared__ int wsum[4];

    const int tid = threadIdx.x;
    const int lane = tid & 63;
    const int b0 = blockIdx.x * P1_EPB;

    if (tid < 256) cnt[tid] = 0;
    __syncthreads();

    // Pass A: load (src,dst) once, histogram coarse buckets
    int sA[P1_ITER], dA[P1_ITER];
#pragma unroll
    for (int j = 0; j < P1_ITER; ++j) {
        int i = b0 + j * P1_TPB + tid;
        int s = 0, d = 0;
        if (i < EE) {
            s = edge_src[i];
            d = edge_dst[i];
            atomicAdd(&cnt[d >> 9], 1);
        }
        sA[j] = s; dA[j] = d;
    }
    __syncthreads();

    // 256-entry exclusive scan: wave-shuffle scan (waves 0-3) + tiny combine
    int c = (tid < 256) ? cnt[tid] : 0;
    int x = c;
#pragma unroll
    for (int o = 1; o < 64; o <<= 1) {
        int y = __shfl_up(x, o);
        if (lane >= o) x += y;
    }
    if (tid < 256 && lane == 63) wsum[tid >> 6] = x;
    __syncthreads();
    if (tid < 256) {
        int w4 = tid >> 6;
        int add = 0;
        if (w4 > 0) add += wsum[0];
        if (w4 > 1) add += wsum[1];
        if (w4 > 2) add += wsum[2];
        int excl = x - c + add;
        cur[tid]   = excl;
        scanv[tid] = excl;
        if (tid < NBUCK) basearr[tid] = c ? atomicAdd(&bcur[tid], c) : 0;
    }
    __syncthreads();

    float4 w00 = ((const float4*)Wae)[0], w01 = ((const float4*)Wae)[1];
    float4 w10 = ((const float4*)Wae)[2], w11 = ((const float4*)Wae)[3];

    // Pass B prefetch: issue ALL global loads before any compute
    float4 e0v[P1_ITER], e1v[P1_ITER];
    float2 asv[P1_ITER], adv[P1_ITER];
#pragma unroll
    for (int j = 0; j < P1_ITER; ++j) {
        int i = b0 + j * P1_TPB + tid;
        if (i >= EE) continue;
        e0v[j] = ((const float4*)feat_edge)[i * 2 + 0];
        e1v[j] = ((const float4*)feat_edge)[i * 2 + 1];
        asv[j] = ((const float2*)a_src)[sA[j]];
        adv[j] = ((const float2*)a_dst)[dA[j]];
    }

    // Pass B compute: scores, scatter records into LDS at sorted position
#pragma unroll
    for (int j = 0; j < P1_ITER; ++j) {
        int i = b0 + j * P1_TPB + tid;
        if (i >= EE) continue;
        int s = sA[j], d = dA[j];
        float4 e0 = e0v[j], e1 = e1v[j];
        float ae0 = e0.x*w00.x + e0.y*w00.y + e0.z*w00.z + e0.w*w00.w
                  + e1.x*w01.x + e1.y*w01.y + e1.z*w01.z + e1.w*w01.w;
        float ae1 = e0.x*w10.x + e0.y*w10.y + e0.z*w10.z + e0.w*w10.w
                  + e1.x*w11.x + e1.y*w11.y + e1.z*w11.z + e1.w*w11.w;
        float v0 = asv[j].x + adv[j].x + ae0;
        float v1 = asv[j].y + adv[j].y + ae1;
        v0 = (v0 >= 0.f) ? v0 : NEG_SLOPE * v0;
        v1 = (v1 >= 0.f) ? v1 : NEG_SLOPE * v1;
        int bk = d >> 9;
        int pos = atomicAdd(&cur[bk], 1);
        rec[pos] = make_uint4((uint)s, (uint)d, f2u(v0), f2u(v1));
    }
    __syncthreads();

    // Pass C: linear write-out; consecutive lanes -> consecutive global addrs
    const int tot = (EE - b0 < P1_EPB) ? (EE - b0) : P1_EPB;
    for (int idx = tid; idx < tot; idx += P1_TPB) {
        uint4 r = rec[idx];
        int bk = (int)(r.y >> 9);
        staging[basearr[bk] + (idx - scanv[bk])] = r;
    }
}

// ---------------------------------------------------------------------------
// Phase 2: fine scatter within bucket (LDS cursors; L2-absorbed writes).
// ---------------------------------------------------------------------------
__global__ __launch_bounds__(1024) void fine_scatter_kernel(
    const int* __restrict__ offsets,
    const uint4* __restrict__ staging, uint4* __restrict__ pairs)
{
    __shared__ int cur[512];
    const int tid = threadIdx.x;
    const int nb0 = blockIdx.x * 512;
    const int ncnt = (NN - nb0 < 512) ? (NN - nb0) : 512;
    for (int i = tid; i < ncnt; i += 1024) cur[i] = offsets[nb0 + i];
    __syncthreads();
    const int lo = offsets[nb0];
    const int hi = offsets[nb0 + ncnt];
    for (int j = lo + tid; j < hi; j += 1024) {
        uint4 it = staging[j];
        int n = (int)it.y - nb0;
        int pos = atomicAdd(&cur[n], 1);
        pairs[pos] = it;
    }
}

// ---------------------------------------------------------------------------
// Fused edge-softmax + aggregation. One wave per dst node.
// ---------------------------------------------------------------------------
__global__ __launch_bounds__(256) void aggregate_fused(
    const int* __restrict__ offsets,
    const uint4* __restrict__ pairs,
    const ushort* __restrict__ hsrc,
    ushort* __restrict__ agg)
{
    __shared__ uint4 stash[4][64];
    const int wave = threadIdx.x >> 6, lane = threadIdx.x & 63;
    const int node = blockIdx.x * 4 + wave;
    if (node >= NN) return;
    const int off = offsets[node], end = offsets[node + 1];
    const int n = end - off;
    const int q4 = lane & 15;         // uint4 column within the 256 B row
    const int grp = lane >> 4;        // edge group 0..3
    const int h0 = (q4 < 8);          // features 8*q4..8*q4+7 -> head0 iff q4<8
    uint4* agg4 = (uint4*)agg;
    if (n <= 0) {
        if (grp == 0) agg4[(size_t)node * 16 + q4] = make_uint4(0u, 0u, 0u, 0u);
        return;
    }
    const uint4* hp4 = (const uint4*)hsrc;

    float a0 = 0.f, a1 = 0.f, a2 = 0.f, a3 = 0.f;
    float a4 = 0.f, a5 = 0.f, a6 = 0.f, a7 = 0.f;
    float z0 = 0.f, z1 = 0.f;

    if (n <= 64) {
        uint4 pr = (lane < n) ? pairs[off + lane]
                              : make_uint4(0u, 0u, 0xff800000u, 0xff800000u);
        float m0 = u2f(pr.z), m1 = u2f(pr.w);
#pragma unroll
        for (int o = 32; o > 0; o >>= 1) {
            m0 = fmaxf(m0, __shfl_xor(m0, o));
            m1 = fmaxf(m1, __shfl_xor(m1, o));
        }
        float ex0 = (lane < n) ? __expf(u2f(pr.z) - m0) : 0.f;
        float ex1 = (lane < n) ? __expf(u2f(pr.w) - m1) : 0.f;
        z0 = ex0; z1 = ex1;
        stash[wave][lane] = make_uint4(pr.x, f2u(ex0), f2u(ex1), 0u);
        __builtin_amdgcn_wave_barrier();
        const int nt = (n + 3) >> 2;
#pragma unroll 4
        for (int t = 0; t < nt; ++t) {
            uint4 st = stash[wave][t * 4 + grp];
            float w = h0 ? u2f(st.y) : u2f(st.z);
            uint4 p = hp4[(size_t)st.x * 16 + q4];
            a0 = fmaf(w, lo_bf(p.x), a0); a1 = fmaf(w, hi_bf(p.x), a1);
            a2 = fmaf(w, lo_bf(p.y), a2); a3 = fmaf(w, hi_bf(p.y), a3);
            a4 = fmaf(w, lo_bf(p.z), a4); a5 = fmaf(w, hi_bf(p.z), a5);
            a6 = fmaf(w, lo_bf(p.w), a6); a7 = fmaf(w, hi_bf(p.w), a7);
        }
    } else {
        float m0 = -INFINITY, m1 = -INFINITY;
        for (int c0 = 0; c0 < n; c0 += 64) {
            if (c0 + lane < n) {
                uint4 pr = pairs[off + c0 + lane];
                m0 = fmaxf(m0, u2f(pr.z));
                m1 = fmaxf(m1, u2f(pr.w));
            }
        }
#pragma unroll
        for (int o = 32; o > 0; o >>= 1) {
            m0 = fmaxf(m0, __shfl_xor(m0, o));
            m1 = fmaxf(m1, __shfl_xor(m1, o));
        }
        for (int c0 = 0; c0 < n; c0 += 64) {
            int cn = n - c0; if (cn > 64) cn = 64;
            uint srcv = 0; float ex0 = 0.f, ex1 = 0.f;
            if (lane < cn) {
                uint4 pr = pairs[off + c0 + lane];
                srcv = pr.x;
                ex0 = __expf(u2f(pr.z) - m0);
                ex1 = __expf(u2f(pr.w) - m1);
                z0 += ex0; z1 += ex1;
            }
            __builtin_amdgcn_wave_barrier();
            stash[wave][lane] = make_uint4(srcv, f2u(ex0), f2u(ex1), 0u);
            __builtin_amdgcn_wave_barrier();
            const int nt = (cn + 3) >> 2;
#pragma unroll 4
            for (int t = 0; t < nt; ++t) {
                uint4 st = stash[wave][t * 4 + grp];
                float w = h0 ? u2f(st.y) : u2f(st.z);
                uint4 p = hp4[(size_t)st.x * 16 + q4];
                a0 = fmaf(w, lo_bf(p.x), a0); a1 = fmaf(w, hi_bf(p.x), a1);
                a2 = fmaf(w, lo_bf(p.y), a2); a3 = fmaf(w, hi_bf(p.y), a3);
                a4 = fmaf(w, lo_bf(p.z), a4); a5 = fmaf(w, hi_bf(p.z), a5);
                a6 = fmaf(w, lo_bf(p.w), a6); a7 = fmaf(w, hi_bf(p.w), a7);
            }
            __builtin_amdgcn_wave_barrier();
        }
    }

    // fold the 4 edge-groups (lanes q4, q4+16, q4+32, q4+48) + z reduce
#pragma unroll
    for (int o = 32; o >= 16; o >>= 1) {
        a0 += __shfl_xor(a0, o); a1 += __shfl_xor(a1, o);
        a2 += __shfl_xor(a2, o); a3 += __shfl_xor(a3, o);
        a4 += __shfl_xor(a4, o); a5 += __shfl_xor(a5, o);
        a6 += __shfl_xor(a6, o); a7 += __shfl_xor(a7, o);
    }
#pragma unroll
    for (int o = 32; o > 0; o >>= 1) {
        z0 += __shfl_xor(z0, o);
        z1 += __shfl_xor(z1, o);
    }
    float zi = h0 ? ((z0 > 0.f) ? 1.f / z0 : 0.f)
                  : ((z1 > 0.f) ? 1.f / z1 : 0.f);
    if (grp == 0) {
        uint4 o4;
        o4.x = ((uint)f2bf(a1 * zi) << 16) | (uint)f2bf(a0 * zi);
        o4.y = ((uint)f2bf(a3 * zi) << 16) | (uint)f2bf(a2 * zi);
        o4.z = ((uint)f2bf(a5 * zi) << 16) | (uint)f2bf(a4 * zi);
        o4.w = ((uint)f2bf(a7 * zi) << 16) | (uint)f2bf(a6 * zi);
        agg4[(size_t)node * 16 + q4] = o4;
    }
}

// ---------------------------------------------------------------------------
extern "C" void kernel_launch(void* const* d_in, const int* in_sizes, int n_in,
                              void* d_out, int out_size, void* d_ws, size_t ws_size,
                              hipStream_t stream) {
    (void)in_sizes; (void)n_in; (void)out_size; (void)ws_size;
    const float* feat_src  = (const float*)d_in[0];
    const float* feat_edge = (const float*)d_in[1];
    const int*   edge_src  = (const int*)d_in[2];
    const int*   edge_dst  = (const int*)d_in[3];
    const float* W_src     = (const float*)d_in[4];
    const float* W_dst     = (const float*)d_in[5];
    const float* b_dst     = (const float*)d_in[6];
    const float* W_attn_src  = (const float*)d_in[7];
    const float* W_attn_dst  = (const float*)d_in[8];
    const float* W_attn_edge = (const float*)d_in[9];
    const float* W_ngnn    = (const float*)d_in[10];
    const float* b_ngnn    = (const float*)d_in[11];
    float* out = (float*)d_out;

    char* base = (char*)d_ws;
    size_t off = 0;
    auto take = [&](size_t bytes) -> void* {
        void* p = base + off;
        off = (off + bytes + 511) & ~(size_t)511;
        return p;
    };
    ushort* h_src_bf = (ushort*)take((size_t)NN * HF * 2);    // 25.6 MB
    ushort* h_dst_bf = (ushort*)take((size_t)NN * HF * 2);    // 25.6 MB (own slot:
                                                              // fused gemm runs BEFORE scatter)
    ushort* agg_bf   = (ushort*)take((size_t)NN * HF * 2);    // 25.6 MB
    uint4*  staging  = (uint4*)take((size_t)EE * 16);         // 25.6 MB
    uint4*  pairs    = (uint4*)take((size_t)EE * 16);         // 25.6 MB
    float*  a_src_b  = (float*)take((size_t)NN * 2 * 4);
    float*  a_dst_b  = (float*)take((size_t)NN * 2 * 4);
    int*    deg      = (int*)take((size_t)NN * 4);
    int*    offsets  = (int*)take((size_t)(NN + 1) * 4);
    int*    bcur     = (int*)take((size_t)NBUCK * 4);
    int*    blockSums= (int*)take(512);
    ushort* Wsrc_bf  = (ushort*)take((size_t)HF * DD * 2);
    ushort* Wdst_bf  = (ushort*)take((size_t)HF * DD * 2);
    ushort* Wngnn_bf = (ushort*)take((size_t)HF * HF * 2);

    const int NB_SCAN = (NN + SCAN_ELEMS - 1) / SCAN_ELEMS;   // 98
    const int GB_E  = (EE + 255) / 256;                       // 6250
    const int GB_M  = (NN + 127) / 128;                       // 782
    const int GB_M64= (NN + 63) / 64;                         // 1563
    const int GB_N4 = (NN + 3) / 4;                           // 25000
    const int GB_P1 = (EE + P1_EPB - 1) / P1_EPB;             // 782
    const int W3_N  = (2 * HF * DD + HF * HF) / 4;            // 20480
    const int GB_W3 = (W3_N + 255) / 256;                     // 80

    // CSR offsets (+ bucket cursor init fused into scan3)
    hipMemsetAsync(deg, 0, (size_t)NN * 4, stream);
    hipLaunchKernelGGL(hist_kernel, dim3(GB_E), dim3(256), 0, stream, edge_dst, deg);
    hipLaunchKernelGGL(scan1_kernel, dim3(NB_SCAN), dim3(256), 0, stream, deg, offsets, blockSums);
    hipLaunchKernelGGL(scan2_kernel, dim3(1), dim3(128), 0, stream, blockSums, NB_SCAN);
    hipLaunchKernelGGL(scan3_kernel, dim3(NB_SCAN), dim3(256), 0, stream, offsets, blockSums, bcur);

    // weight conversions (single launch)
    hipLaunchKernelGGL(f2bf3_kernel, dim3(GB_W3), dim3(256), 0, stream,
                       W_src, W_dst, W_ngnn, Wsrc_bf, Wdst_bf, Wngnn_bf);

    // FUSED attn logits + dual projection GEMM (feat fp32 read exactly once)
    hipLaunchKernelGGL((gemm_dual_attn<DD>), dim3(GB_M64), dim3(256), 0, stream,
                       Wsrc_bf, Wdst_bf, feat_src, W_attn_src, W_attn_dst, b_dst,
                       a_src_b, a_dst_b, h_src_bf, h_dst_bf);

    // edge scores + 2-phase counting sort into CSR order
    hipLaunchKernelGGL(bucket_scatter_kernel, dim3(GB_P1), dim3(P1_TPB), 0, stream,
                       edge_src, edge_dst, feat_edge, a_src_b, a_dst_b, W_attn_edge,
                       bcur, staging);
    hipLaunchKernelGGL(fine_scatter_kernel, dim3(NBUCK), dim3(1024), 0, stream,
                       offsets, staging, pairs);

    // fused softmax + aggregation
    hipLaunchKernelGGL(aggregate_fused, dim3(GB_N4), dim3(256), 0, stream,
                       offsets, pairs, h_src_bf, agg_bf);

    // ngnn + relu + residual -> fp32 out
    hipLaunchKernelGGL(mfma_gemm_ngnn<HF>, dim3(GB_M), dim3(256), 0, stream,
                       Wngnn_bf, agg_bf, b_ngnn, h_dst_bf, out);
}

// Round 6
// 484.566 us; speedup vs baseline: 1.0706x; 1.0706x over previous
//
#include <hip/hip_runtime.h>
#include <hip/hip_bf16.h>
#include <math.h>

#define NN 100000
#define EE 1600000
#define DD 256
#define DEE 8
#define HF 128           // H*F
#define NEG_SLOPE 0.2f
#define NBUCK 196        // ceil(NN/512) coarse dst-buckets (512 nodes each)
#define P1_EPB 2048      // edges per block in bucket_scatter (782 blocks)
#define P1_TPB 512       // threads per block (8 waves -> ~24 waves/CU)
#define P1_ITER (P1_EPB / P1_TPB)   // 4

typedef __bf16 bf16x8 __attribute__((ext_vector_type(8)));
typedef float  f32x4  __attribute__((ext_vector_type(4)));

__device__ inline ushort f2bf(float f) {          // round-to-nearest-even
    uint32_t x = __builtin_bit_cast(uint32_t, f);
    x += 0x7fffu + ((x >> 16) & 1u);
    return (ushort)(x >> 16);
}
__device__ inline float bf2f(ushort u) {
    uint32_t x = ((uint32_t)u) << 16;
    return __builtin_bit_cast(float, x);
}
__device__ inline float u2f(uint u) { return __builtin_bit_cast(float, u); }
__device__ inline uint f2u(float f) { return __builtin_bit_cast(uint, f); }
__device__ inline float lo_bf(uint p) { return __builtin_bit_cast(float, p << 16); }
__device__ inline float hi_bf(uint p) { return __builtin_bit_cast(float, p & 0xffff0000u); }

__device__ inline void load_lds16(const void* g, void* l) {
    __builtin_amdgcn_global_load_lds(
        (const __attribute__((address_space(1))) void*)g,
        (__attribute__((address_space(3))) void*)l, 16, 0, 0);
}

// ---------------------------------------------------------------------------
// fp32 -> bf16 for the 3 weight matrices in one launch
// ---------------------------------------------------------------------------
__global__ __launch_bounds__(256) void f2bf3_kernel(
    const float* __restrict__ wa, const float* __restrict__ wb,
    const float* __restrict__ wc,
    ushort* __restrict__ oa, ushort* __restrict__ ob, ushort* __restrict__ oc)
{
    int i = (blockIdx.x * 256 + threadIdx.x) * 4;
    const int na = HF * DD, nb2 = 2 * HF * DD, nc3 = 2 * HF * DD + HF * HF;
    const float* src; ushort* dst; int o;
    if (i < na)       { src = wa; dst = oa; o = i; }
    else if (i < nb2) { src = wb; dst = ob; o = i - na; }
    else if (i < nc3) { src = wc; dst = oc; o = i - nb2; }
    else return;
    float4 v = *(const float4*)(src + o);
    ushort4 u;
    u.x = f2bf(v.x); u.y = f2bf(v.y); u.z = f2bf(v.z); u.w = f2bf(v.w);
    *(ushort4*)(dst + o) = u;
}

// ---------------------------------------------------------------------------
// FUSED: attn logits + dual projection GEMM. One 64-node tile per block.
// B staged PER K-STEP (4 KB) via registers: fp32 feat octet -> logit partial
// FMAs (fp32 precision, same op order as verified build) -> bf16 ds_write.
// LDS = As 16K + Bs 4K + wlds 4K = 24 KB (was 52 KB -> occupancy collapse).
// ---------------------------------------------------------------------------
template<int K>
__global__ __launch_bounds__(256) void gemm_dual_attn(
    const ushort* __restrict__ W0,     // [128][K] bf16
    const ushort* __restrict__ W1,     // [128][K] bf16
    const float*  __restrict__ Xf,     // [NN][K] fp32 feat
    const float*  __restrict__ Was,    // [2][K] fp32
    const float*  __restrict__ Wad,    // [2][K] fp32
    const float*  __restrict__ bias1,  // [128]
    float* __restrict__ a_src, float* __restrict__ a_dst,
    ushort* __restrict__ out0, ushort* __restrict__ out1)
{
    __shared__ ushort As[2][128 * 32];   // 16 KB, per-step W slabs
    __shared__ ushort Bs[64 * 32];       // 4 KB, per-step B tile
    __shared__ float  wlds[4][K];        // 4 KB, attn vectors

    const int tid  = threadIdx.x;
    const int lane = tid & 63, wv = tid >> 6;
    const int wm = wv >> 1, wn = wv & 1;
    const int r = lane & 15, quad = lane >> 4;
    const int m0 = blockIdx.x * 64;

    // preload attn vectors: 4 x K floats, 1 float4 per thread
    {
        int vec = tid >> 6, e = (tid & 63) * 4;
        const float* src = (vec < 2) ? (Was + vec * K + e) : (Wad + (vec - 2) * K + e);
        *(float4*)&wlds[vec][e] = *(const float4*)src;
    }

    // thread -> (node = tid>>2, k-octet = (tid&3)*8) for B staging + logits
    const int node = tid >> 2;
    const int kq   = (tid & 3) * 8;
    int gm = m0 + node; gm = gm < NN ? gm : NN - 1;
    const float* frow = Xf + (size_t)gm * K;

    float p0 = 0.f, p1 = 0.f, p2 = 0.f, p3 = 0.f;
    f32x4 acc[2][4][2] = {};

    // prime first step's feat octet
    float4 fa = *(const float4*)(frow + kq);
    float4 fb = *(const float4*)(frow + kq + 4);
    __syncthreads();   // wlds ready

    for (int k0 = 0; k0 < K; k0 += 32) {
        const int k = k0 + kq;
        // logit partials while fp32 is live (same op order as verified build)
        {
            float4 wv0a = *(const float4*)&wlds[0][k];
            float4 wv0b = *(const float4*)&wlds[0][k + 4];
            float4 wv1a = *(const float4*)&wlds[1][k];
            float4 wv1b = *(const float4*)&wlds[1][k + 4];
            float4 wv2a = *(const float4*)&wlds[2][k];
            float4 wv2b = *(const float4*)&wlds[2][k + 4];
            float4 wv3a = *(const float4*)&wlds[3][k];
            float4 wv3b = *(const float4*)&wlds[3][k + 4];
            p0 += fa.x*wv0a.x + fa.y*wv0a.y + fa.z*wv0a.z + fa.w*wv0a.w
                + fb.x*wv0b.x + fb.y*wv0b.y + fb.z*wv0b.z + fb.w*wv0b.w;
            p1 += fa.x*wv1a.x + fa.y*wv1a.y + fa.z*wv1a.z + fa.w*wv1a.w
                + fb.x*wv1b.x + fb.y*wv1b.y + fb.z*wv1b.z + fb.w*wv1b.w;
            p2 += fa.x*wv2a.x + fa.y*wv2a.y + fa.z*wv2a.z + fa.w*wv2a.w
                + fb.x*wv2b.x + fb.y*wv2b.y + fb.z*wv2b.z + fb.w*wv2b.w;
            p3 += fa.x*wv3a.x + fa.y*wv3a.y + fa.z*wv3a.z + fa.w*wv3a.w
                + fb.x*wv3b.x + fb.y*wv3b.y + fb.z*wv3b.z + fb.w*wv3b.w;
        }
        // convert + stage this K-step's B tile (linear 16 B/lane, conflict-free)
        {
            uint q0 = ((uint)f2bf(fa.y) << 16) | f2bf(fa.x);
            uint q1 = ((uint)f2bf(fa.w) << 16) | f2bf(fa.z);
            uint q2 = ((uint)f2bf(fb.y) << 16) | f2bf(fb.x);
            uint q3 = ((uint)f2bf(fb.w) << 16) | f2bf(fb.z);
            *(uint4*)&Bs[node * 32 + kq] = make_uint4(q0, q1, q2, q3);
        }
        // stage W slabs for this K-step
#pragma unroll
        for (int t = 0; t < 2; ++t) {
            int is  = wv + t * 4;
            int row = is * 16 + (lane >> 2);
            int ko  = k0 + (lane & 3) * 8;
            load_lds16(W0 + (size_t)row * K + ko, &As[0][is * 512]);
            load_lds16(W1 + (size_t)row * K + ko, &As[1][is * 512]);
        }
        __syncthreads();

        // prefetch next step's feat octet (hides under MFMA block)
        if (k0 + 32 < K) {
            fa = *(const float4*)(frow + k0 + 32 + kq);
            fb = *(const float4*)(frow + k0 + 36 + kq);
        }

        bf16x8 a[2][4], b[2];
#pragma unroll
        for (int i = 0; i < 4; ++i) {
            a[0][i] = __builtin_bit_cast(bf16x8,
                      *(const f32x4*)&As[0][(wm * 64 + i * 16 + r) * 32 + quad * 8]);
            a[1][i] = __builtin_bit_cast(bf16x8,
                      *(const f32x4*)&As[1][(wm * 64 + i * 16 + r) * 32 + quad * 8]);
        }
#pragma unroll
        for (int j = 0; j < 2; ++j)
            b[j] = __builtin_bit_cast(bf16x8,
                   *(const f32x4*)&Bs[(wn * 32 + j * 16 + r) * 32 + quad * 8]);
#pragma unroll
        for (int s = 0; s < 2; ++s)
#pragma unroll
            for (int i = 0; i < 4; ++i)
#pragma unroll
                for (int j = 0; j < 2; ++j)
                    acc[s][i][j] = __builtin_amdgcn_mfma_f32_16x16x32_bf16(
                        a[s][i], b[j], acc[s][i][j], 0, 0, 0);
        __syncthreads();
    }

    // fold the 4 k-octet threads of each node + store logits
    p0 += __shfl_xor(p0, 1); p0 += __shfl_xor(p0, 2);
    p1 += __shfl_xor(p1, 1); p1 += __shfl_xor(p1, 2);
    p2 += __shfl_xor(p2, 1); p2 += __shfl_xor(p2, 2);
    p3 += __shfl_xor(p3, 1); p3 += __shfl_xor(p3, 2);
    if ((tid & 3) == 0 && m0 + node < NN) {
        *(float2*)&a_src[(size_t)(m0 + node) * 2] = make_float2(p0, p1);
        *(float2*)&a_dst[(size_t)(m0 + node) * 2] = make_float2(p2, p3);
    }

#pragma unroll
    for (int s = 0; s < 2; ++s) {
        ushort* outp = s ? out1 : out0;
#pragma unroll
        for (int i = 0; i < 4; ++i) {
            int fbase = wm * 64 + i * 16 + quad * 4;
            float4 bv = make_float4(0.f, 0.f, 0.f, 0.f);
            if (s == 1) bv = *(const float4*)(bias1 + fbase);
#pragma unroll
            for (int j = 0; j < 2; ++j) {
                int node2 = m0 + wn * 32 + j * 16 + r;
                if (node2 >= NN) continue;
                f32x4 v = acc[s][i][j];
                v[0] += bv.x; v[1] += bv.y; v[2] += bv.z; v[3] += bv.w;
                ushort4 o;
                o.x = f2bf(v[0]); o.y = f2bf(v[1]); o.z = f2bf(v[2]); o.w = f2bf(v[3]);
                *(ushort4*)(outp + (size_t)node2 * HF + fbase) = o;
            }
        }
    }
}

// ---------------------------------------------------------------------------
// ngnn GEMM (K=128): fp32 out[node][f] = relu(acc+bias) + bf2f(resid)
// ---------------------------------------------------------------------------
template<int K>
__global__ __launch_bounds__(256) void mfma_gemm_ngnn(
    const ushort* __restrict__ Wb,
    const ushort* __restrict__ Xb,
    const float*  __restrict__ bias,
    const ushort* __restrict__ resid,
    float* __restrict__ outp)
{
    __shared__ ushort As[128 * 32];
    __shared__ ushort Bs[128 * 32];

    const int tid  = threadIdx.x;
    const int lane = tid & 63, wv = tid >> 6;
    const int wm = wv >> 1, wn = wv & 1;
    const int r = lane & 15, quad = lane >> 4;
    const int m0 = blockIdx.x * 128;

    f32x4 acc[4][4] = {};

    for (int k0 = 0; k0 < K; k0 += 32) {
#pragma unroll
        for (int t = 0; t < 2; ++t) {
            int is  = wv + t * 4;
            int row = is * 16 + (lane >> 2);
            int ko  = k0 + (lane & 3) * 8;
            load_lds16(Wb + (size_t)row * K + ko, &As[is * 512]);
            int gm = m0 + row; gm = gm < NN ? gm : NN - 1;
            load_lds16(Xb + (size_t)gm * K + ko, &Bs[is * 512]);
        }
        __syncthreads();
        bf16x8 a[4], b[4];
#pragma unroll
        for (int i = 0; i < 4; ++i) {
            a[i] = __builtin_bit_cast(bf16x8,
                   *(const f32x4*)&As[(wm * 64 + i * 16 + r) * 32 + quad * 8]);
            b[i] = __builtin_bit_cast(bf16x8,
                   *(const f32x4*)&Bs[(wn * 64 + i * 16 + r) * 32 + quad * 8]);
        }
#pragma unroll
        for (int i = 0; i < 4; ++i)
#pragma unroll
            for (int j = 0; j < 4; ++j)
                acc[i][j] = __builtin_amdgcn_mfma_f32_16x16x32_bf16(
                    a[i], b[j], acc[i][j], 0, 0, 0);
        __syncthreads();
    }

#pragma unroll
    for (int i = 0; i < 4; ++i) {
        int fbase = wm * 64 + i * 16 + quad * 4;
        float4 bv = *(const float4*)(bias + fbase);
#pragma unroll
        for (int j = 0; j < 4; ++j) {
            int node = m0 + wn * 64 + j * 16 + r;
            if (node >= NN) continue;
            f32x4 v = acc[i][j];
            ushort4 rs = *(const ushort4*)(resid + (size_t)node * HF + fbase);
            float4 o;
            o.x = fmaxf(v[0] + bv.x, 0.f) + bf2f(rs.x);
            o.y = fmaxf(v[1] + bv.y, 0.f) + bf2f(rs.y);
            o.z = fmaxf(v[2] + bv.z, 0.f) + bf2f(rs.z);
            o.w = fmaxf(v[3] + bv.w, 0.f) + bf2f(rs.w);
            *(float4*)(outp + (size_t)node * HF + fbase) = o;
        }
    }
}

// ---------------------------------------------------------------------------
// CSR degree histogram + scan
// ---------------------------------------------------------------------------
__global__ __launch_bounds__(256) void hist_kernel(
    const int* __restrict__ edge_dst, int* __restrict__ deg)
{
    int i = blockIdx.x * 256 + threadIdx.x;
    if (i < EE) atomicAdd(&deg[edge_dst[i]], 1);
}

#define SCAN_ELEMS 1024
__global__ __launch_bounds__(256) void scan1_kernel(
    const int* __restrict__ deg, int* __restrict__ offsets, int* __restrict__ blockSums)
{
    __shared__ int sd[256];
    int tid = threadIdx.x;
    int base = blockIdx.x * SCAN_ELEMS + tid * 4;
    int v[4];
#pragma unroll
    for (int c = 0; c < 4; ++c) v[c] = (base + c < NN) ? deg[base + c] : 0;
    int tsum = v[0] + v[1] + v[2] + v[3];
    sd[tid] = tsum;
    __syncthreads();
    for (int o = 1; o < 256; o <<= 1) {
        int x = (tid >= o) ? sd[tid - o] : 0;
        __syncthreads();
        sd[tid] += x;
        __syncthreads();
    }
    int excl = sd[tid] - tsum;
    int run = excl;
#pragma unroll
    for (int c = 0; c < 4; ++c) {
        if (base + c < NN) offsets[base + c] = run;
        run += v[c];
    }
    if (tid == 255) blockSums[blockIdx.x] = sd[255];
}

__global__ __launch_bounds__(128) void scan2_kernel(int* __restrict__ blockSums, int nb)
{
    __shared__ int sd[128];
    int tid = threadIdx.x;
    int tv = (tid < nb) ? blockSums[tid] : 0;
    sd[tid] = tv;
    __syncthreads();
    for (int o = 1; o < 128; o <<= 1) {
        int x = (tid >= o) ? sd[tid - o] : 0;
        __syncthreads();
        sd[tid] += x;
        __syncthreads();
    }
    if (tid < nb) blockSums[tid] = sd[tid] - tv;
}

// scan3 + bucket-cursor init fused
__global__ __launch_bounds__(256) void scan3_kernel(
    int* __restrict__ offsets, const int* __restrict__ blockSums,
    int* __restrict__ bcur)
{
    int tid = threadIdx.x;
    int base = blockIdx.x * SCAN_ELEMS + tid * 4;
    int add = blockSums[blockIdx.x];
#pragma unroll
    for (int c = 0; c < 4; ++c) {
        int idx = base + c;
        if (idx < NN) {
            int v = offsets[idx] + add;
            offsets[idx] = v;
            if ((idx & 511) == 0) bcur[idx >> 9] = v;
        }
    }
    if (blockIdx.x == 0 && tid == 0) offsets[NN] = EE;
}

// ---------------------------------------------------------------------------
// Phase 1: fused edge-score + coarse bucket scatter.
// ---------------------------------------------------------------------------
__global__ __launch_bounds__(P1_TPB) void bucket_scatter_kernel(
    const int* __restrict__ edge_src, const int* __restrict__ edge_dst,
    const float* __restrict__ feat_edge,
    const float* __restrict__ a_src, const float* __restrict__ a_dst,
    const float* __restrict__ Wae,
    int* __restrict__ bcur, uint4* __restrict__ staging)
{
    __shared__ uint4 rec[P1_EPB];      // 32 KB in-block sorted records
    __shared__ int cnt[256];
    __shared__ int scanv[256];         // exclusive bucket start within block
    __shared__ int cur[256];           // running cursor for LDS scatter
    __shared__ int basearr[256];       // global base per bucket
    __shared__ int wsum[4];

    const int tid = threadIdx.x;
    const int lane = tid & 63;
    const int b0 = blockIdx.x * P1_EPB;

    if (tid < 256) cnt[tid] = 0;
    __syncthreads();

    // Pass A: load (src,dst) once, histogram coarse buckets
    int sA[P1_ITER], dA[P1_ITER];
#pragma unroll
    for (int j = 0; j < P1_ITER; ++j) {
        int i = b0 + j * P1_TPB + tid;
        int s = 0, d = 0;
        if (i < EE) {
            s = edge_src[i];
            d = edge_dst[i];
            atomicAdd(&cnt[d >> 9], 1);
        }
        sA[j] = s; dA[j] = d;
    }
    __syncthreads();

    // 256-entry exclusive scan: wave-shuffle scan (waves 0-3) + tiny combine
    int c = (tid < 256) ? cnt[tid] : 0;
    int x = c;
#pragma unroll
    for (int o = 1; o < 64; o <<= 1) {
        int y = __shfl_up(x, o);
        if (lane >= o) x += y;
    }
    if (tid < 256 && lane == 63) wsum[tid >> 6] = x;
    __syncthreads();
    if (tid < 256) {
        int w4 = tid >> 6;
        int add = 0;
        if (w4 > 0) add += wsum[0];
        if (w4 > 1) add += wsum[1];
        if (w4 > 2) add += wsum[2];
        int excl = x - c + add;
        cur[tid]   = excl;
        scanv[tid] = excl;
        if (tid < NBUCK) basearr[tid] = c ? atomicAdd(&bcur[tid], c) : 0;
    }
    __syncthreads();

    float4 w00 = ((const float4*)Wae)[0], w01 = ((const float4*)Wae)[1];
    float4 w10 = ((const float4*)Wae)[2], w11 = ((const float4*)Wae)[3];

    // Pass B prefetch: issue ALL global loads before any compute
    float4 e0v[P1_ITER], e1v[P1_ITER];
    float2 asv[P1_ITER], adv[P1_ITER];
#pragma unroll
    for (int j = 0; j < P1_ITER; ++j) {
        int i = b0 + j * P1_TPB + tid;
        if (i >= EE) continue;
        e0v[j] = ((const float4*)feat_edge)[i * 2 + 0];
        e1v[j] = ((const float4*)feat_edge)[i * 2 + 1];
        asv[j] = ((const float2*)a_src)[sA[j]];
        adv[j] = ((const float2*)a_dst)[dA[j]];
    }

    // Pass B compute: scores, scatter records into LDS at sorted position
#pragma unroll
    for (int j = 0; j < P1_ITER; ++j) {
        int i = b0 + j * P1_TPB + tid;
        if (i >= EE) continue;
        int s = sA[j], d = dA[j];
        float4 e0 = e0v[j], e1 = e1v[j];
        float ae0 = e0.x*w00.x + e0.y*w00.y + e0.z*w00.z + e0.w*w00.w
                  + e1.x*w01.x + e1.y*w01.y + e1.z*w01.z + e1.w*w01.w;
        float ae1 = e0.x*w10.x + e0.y*w10.y + e0.z*w10.z + e0.w*w10.w
                  + e1.x*w11.x + e1.y*w11.y + e1.z*w11.z + e1.w*w11.w;
        float v0 = asv[j].x + adv[j].x + ae0;
        float v1 = asv[j].y + adv[j].y + ae1;
        v0 = (v0 >= 0.f) ? v0 : NEG_SLOPE * v0;
        v1 = (v1 >= 0.f) ? v1 : NEG_SLOPE * v1;
        int bk = d >> 9;
        int pos = atomicAdd(&cur[bk], 1);
        rec[pos] = make_uint4((uint)s, (uint)d, f2u(v0), f2u(v1));
    }
    __syncthreads();

    // Pass C: linear write-out; consecutive lanes -> consecutive global addrs
    const int tot = (EE - b0 < P1_EPB) ? (EE - b0) : P1_EPB;
    for (int idx = tid; idx < tot; idx += P1_TPB) {
        uint4 r = rec[idx];
        int bk = (int)(r.y >> 9);
        staging[basearr[bk] + (idx - scanv[bk])] = r;
    }
}

// ---------------------------------------------------------------------------
// Phase 2: fine scatter within bucket (LDS cursors; L2-absorbed writes).
// ---------------------------------------------------------------------------
__global__ __launch_bounds__(1024) void fine_scatter_kernel(
    const int* __restrict__ offsets,
    const uint4* __restrict__ staging, uint4* __restrict__ pairs)
{
    __shared__ int cur[512];
    const int tid = threadIdx.x;
    const int nb0 = blockIdx.x * 512;
    const int ncnt = (NN - nb0 < 512) ? (NN - nb0) : 512;
    for (int i = tid; i < ncnt; i += 1024) cur[i] = offsets[nb0 + i];
    __syncthreads();
    const int lo = offsets[nb0];
    const int hi = offsets[nb0 + ncnt];
    for (int j = lo + tid; j < hi; j += 1024) {
        uint4 it = staging[j];
        int n = (int)it.y - nb0;
        int pos = atomicAdd(&cur[n], 1);
        pairs[pos] = it;
    }
}

// ---------------------------------------------------------------------------
// Fused edge-softmax + aggregation. One wave per dst node.
// ---------------------------------------------------------------------------
__global__ __launch_bounds__(256) void aggregate_fused(
    const int* __restrict__ offsets,
    const uint4* __restrict__ pairs,
    const ushort* __restrict__ hsrc,
    ushort* __restrict__ agg)
{
    __shared__ uint4 stash[4][64];
    const int wave = threadIdx.x >> 6, lane = threadIdx.x & 63;
    const int node = blockIdx.x * 4 + wave;
    if (node >= NN) return;
    const int off = offsets[node], end = offsets[node + 1];
    const int n = end - off;
    const int q4 = lane & 15;         // uint4 column within the 256 B row
    const int grp = lane >> 4;        // edge group 0..3
    const int h0 = (q4 < 8);          // features 8*q4..8*q4+7 -> head0 iff q4<8
    uint4* agg4 = (uint4*)agg;
    if (n <= 0) {
        if (grp == 0) agg4[(size_t)node * 16 + q4] = make_uint4(0u, 0u, 0u, 0u);
        return;
    }
    const uint4* hp4 = (const uint4*)hsrc;

    float a0 = 0.f, a1 = 0.f, a2 = 0.f, a3 = 0.f;
    float a4 = 0.f, a5 = 0.f, a6 = 0.f, a7 = 0.f;
    float z0 = 0.f, z1 = 0.f;

    if (n <= 64) {
        uint4 pr = (lane < n) ? pairs[off + lane]
                              : make_uint4(0u, 0u, 0xff800000u, 0xff800000u);
        float m0 = u2f(pr.z), m1 = u2f(pr.w);
#pragma unroll
        for (int o = 32; o > 0; o >>= 1) {
            m0 = fmaxf(m0, __shfl_xor(m0, o));
            m1 = fmaxf(m1, __shfl_xor(m1, o));
        }
        float ex0 = (lane < n) ? __expf(u2f(pr.z) - m0) : 0.f;
        float ex1 = (lane < n) ? __expf(u2f(pr.w) - m1) : 0.f;
        z0 = ex0; z1 = ex1;
        stash[wave][lane] = make_uint4(pr.x, f2u(ex0), f2u(ex1), 0u);
        __builtin_amdgcn_wave_barrier();
        const int nt = (n + 3) >> 2;
#pragma unroll 4
        for (int t = 0; t < nt; ++t) {
            uint4 st = stash[wave][t * 4 + grp];
            float w = h0 ? u2f(st.y) : u2f(st.z);
            uint4 p = hp4[(size_t)st.x * 16 + q4];
            a0 = fmaf(w, lo_bf(p.x), a0); a1 = fmaf(w, hi_bf(p.x), a1);
            a2 = fmaf(w, lo_bf(p.y), a2); a3 = fmaf(w, hi_bf(p.y), a3);
            a4 = fmaf(w, lo_bf(p.z), a4); a5 = fmaf(w, hi_bf(p.z), a5);
            a6 = fmaf(w, lo_bf(p.w), a6); a7 = fmaf(w, hi_bf(p.w), a7);
        }
    } else {
        float m0 = -INFINITY, m1 = -INFINITY;
        for (int c0 = 0; c0 < n; c0 += 64) {
            if (c0 + lane < n) {
                uint4 pr = pairs[off + c0 + lane];
                m0 = fmaxf(m0, u2f(pr.z));
                m1 = fmaxf(m1, u2f(pr.w));
            }
        }
#pragma unroll
        for (int o = 32; o > 0; o >>= 1) {
            m0 = fmaxf(m0, __shfl_xor(m0, o));
            m1 = fmaxf(m1, __shfl_xor(m1, o));
        }
        for (int c0 = 0; c0 < n; c0 += 64) {
            int cn = n - c0; if (cn > 64) cn = 64;
            uint srcv = 0; float ex0 = 0.f, ex1 = 0.f;
            if (lane < cn) {
                uint4 pr = pairs[off + c0 + lane];
                srcv = pr.x;
                ex0 = __expf(u2f(pr.z) - m0);
                ex1 = __expf(u2f(pr.w) - m1);
                z0 += ex0; z1 += ex1;
            }
            __builtin_amdgcn_wave_barrier();
            stash[wave][lane] = make_uint4(srcv, f2u(ex0), f2u(ex1), 0u);
            __builtin_amdgcn_wave_barrier();
            const int nt = (cn + 3) >> 2;
#pragma unroll 4
            for (int t = 0; t < nt; ++t) {
                uint4 st = stash[wave][t * 4 + grp];
                float w = h0 ? u2f(st.y) : u2f(st.z);
                uint4 p = hp4[(size_t)st.x * 16 + q4];
                a0 = fmaf(w, lo_bf(p.x), a0); a1 = fmaf(w, hi_bf(p.x), a1);
                a2 = fmaf(w, lo_bf(p.y), a2); a3 = fmaf(w, hi_bf(p.y), a3);
                a4 = fmaf(w, lo_bf(p.z), a4); a5 = fmaf(w, hi_bf(p.z), a5);
                a6 = fmaf(w, lo_bf(p.w), a6); a7 = fmaf(w, hi_bf(p.w), a7);
            }
            __builtin_amdgcn_wave_barrier();
        }
    }

    // fold the 4 edge-groups (lanes q4, q4+16, q4+32, q4+48) + z reduce
#pragma unroll
    for (int o = 32; o >= 16; o >>= 1) {
        a0 += __shfl_xor(a0, o); a1 += __shfl_xor(a1, o);
        a2 += __shfl_xor(a2, o); a3 += __shfl_xor(a3, o);
        a4 += __shfl_xor(a4, o); a5 += __shfl_xor(a5, o);
        a6 += __shfl_xor(a6, o); a7 += __shfl_xor(a7, o);
    }
#pragma unroll
    for (int o = 32; o > 0; o >>= 1) {
        z0 += __shfl_xor(z0, o);
        z1 += __shfl_xor(z1, o);
    }
    float zi = h0 ? ((z0 > 0.f) ? 1.f / z0 : 0.f)
                  : ((z1 > 0.f) ? 1.f / z1 : 0.f);
    if (grp == 0) {
        uint4 o4;
        o4.x = ((uint)f2bf(a1 * zi) << 16) | (uint)f2bf(a0 * zi);
        o4.y = ((uint)f2bf(a3 * zi) << 16) | (uint)f2bf(a2 * zi);
        o4.z = ((uint)f2bf(a5 * zi) << 16) | (uint)f2bf(a4 * zi);
        o4.w = ((uint)f2bf(a7 * zi) << 16) | (uint)f2bf(a6 * zi);
        agg4[(size_t)node * 16 + q4] = o4;
    }
}

// ---------------------------------------------------------------------------
extern "C" void kernel_launch(void* const* d_in, const int* in_sizes, int n_in,
                              void* d_out, int out_size, void* d_ws, size_t ws_size,
                              hipStream_t stream) {
    (void)in_sizes; (void)n_in; (void)out_size; (void)ws_size;
    const float* feat_src  = (const float*)d_in[0];
    const float* feat_edge = (const float*)d_in[1];
    const int*   edge_src  = (const int*)d_in[2];
    const int*   edge_dst  = (const int*)d_in[3];
    const float* W_src     = (const float*)d_in[4];
    const float* W_dst     = (const float*)d_in[5];
    const float* b_dst     = (const float*)d_in[6];
    const float* W_attn_src  = (const float*)d_in[7];
    const float* W_attn_dst  = (const float*)d_in[8];
    const float* W_attn_edge = (const float*)d_in[9];
    const float* W_ngnn    = (const float*)d_in[10];
    const float* b_ngnn    = (const float*)d_in[11];
    float* out = (float*)d_out;

    char* base = (char*)d_ws;
    size_t off = 0;
    auto take = [&](size_t bytes) -> void* {
        void* p = base + off;
        off = (off + bytes + 511) & ~(size_t)511;
        return p;
    };
    ushort* h_src_bf = (ushort*)take((size_t)NN * HF * 2);    // 25.6 MB
    ushort* h_dst_bf = (ushort*)take((size_t)NN * HF * 2);    // 25.6 MB
    ushort* agg_bf   = (ushort*)take((size_t)NN * HF * 2);    // 25.6 MB
    uint4*  staging  = (uint4*)take((size_t)EE * 16);         // 25.6 MB
    uint4*  pairs    = (uint4*)take((size_t)EE * 16);         // 25.6 MB
    float*  a_src_b  = (float*)take((size_t)NN * 2 * 4);
    float*  a_dst_b  = (float*)take((size_t)NN * 2 * 4);
    int*    deg      = (int*)take((size_t)NN * 4);
    int*    offsets  = (int*)take((size_t)(NN + 1) * 4);
    int*    bcur     = (int*)take((size_t)NBUCK * 4);
    int*    blockSums= (int*)take(512);
    ushort* Wsrc_bf  = (ushort*)take((size_t)HF * DD * 2);
    ushort* Wdst_bf  = (ushort*)take((size_t)HF * DD * 2);
    ushort* Wngnn_bf = (ushort*)take((size_t)HF * HF * 2);

    const int NB_SCAN = (NN + SCAN_ELEMS - 1) / SCAN_ELEMS;   // 98
    const int GB_E  = (EE + 255) / 256;                       // 6250
    const int GB_M  = (NN + 127) / 128;                       // 782
    const int GB_M64= (NN + 63) / 64;                         // 1563
    const int GB_N4 = (NN + 3) / 4;                           // 25000
    const int GB_P1 = (EE + P1_EPB - 1) / P1_EPB;             // 782
    const int W3_N  = (2 * HF * DD + HF * HF) / 4;            // 20480
    const int GB_W3 = (W3_N + 255) / 256;                     // 80

    // CSR offsets (+ bucket cursor init fused into scan3)
    hipMemsetAsync(deg, 0, (size_t)NN * 4, stream);
    hipLaunchKernelGGL(hist_kernel, dim3(GB_E), dim3(256), 0, stream, edge_dst, deg);
    hipLaunchKernelGGL(scan1_kernel, dim3(NB_SCAN), dim3(256), 0, stream, deg, offsets, blockSums);
    hipLaunchKernelGGL(scan2_kernel, dim3(1), dim3(128), 0, stream, blockSums, NB_SCAN);
    hipLaunchKernelGGL(scan3_kernel, dim3(NB_SCAN), dim3(256), 0, stream, offsets, blockSums, bcur);

    // weight conversions (single launch)
    hipLaunchKernelGGL(f2bf3_kernel, dim3(GB_W3), dim3(256), 0, stream,
                       W_src, W_dst, W_ngnn, Wsrc_bf, Wdst_bf, Wngnn_bf);

    // FUSED attn logits + dual projection GEMM (feat fp32 read exactly once)
    hipLaunchKernelGGL((gemm_dual_attn<DD>), dim3(GB_M64), dim3(256), 0, stream,
                       Wsrc_bf, Wdst_bf, feat_src, W_attn_src, W_attn_dst, b_dst,
                       a_src_b, a_dst_b, h_src_bf, h_dst_bf);

    // edge scores + 2-phase counting sort into CSR order
    hipLaunchKernelGGL(bucket_scatter_kernel, dim3(GB_P1), dim3(P1_TPB), 0, stream,
                       edge_src, edge_dst, feat_edge, a_src_b, a_dst_b, W_attn_edge,
                       bcur, staging);
    hipLaunchKernelGGL(fine_scatter_kernel, dim3(NBUCK), dim3(1024), 0, stream,
                       offsets, staging, pairs);

    // fused softmax + aggregation
    hipLaunchKernelGGL(aggregate_fused, dim3(GB_N4), dim3(256), 0, stream,
                       offsets, pairs, h_src_bf, agg_bf);

    // ngnn + relu + residual -> fp32 out
    hipLaunchKernelGGL(mfma_gemm_ngnn<HF>, dim3(GB_M), dim3(256), 0, stream,
                       Wngnn_bf, agg_bf, b_ngnn, h_dst_bf, out);
}

// Round 7
// 484.107 us; speedup vs baseline: 1.0716x; 1.0009x over previous
//
#include <hip/hip_runtime.h>
#include <hip/hip_bf16.h>
#include <math.h>

#define NN 100000
#define EE 1600000
#define DD 256
#define DEE 8
#define HF 128           // H*F
#define NEG_SLOPE 0.2f
#define NBUCK 196        // ceil(NN/512) coarse dst-buckets (512 nodes each)
#define P1_EPB 2048      // edges per block in bucket_scatter (782 blocks)
#define P1_TPB 512       // threads per block (8 waves -> ~24 waves/CU)
#define P1_ITER (P1_EPB / P1_TPB)   // 4

typedef __bf16 bf16x8 __attribute__((ext_vector_type(8)));
typedef float  f32x4  __attribute__((ext_vector_type(4)));

__device__ inline ushort f2bf(float f) {          // round-to-nearest-even
    uint32_t x = __builtin_bit_cast(uint32_t, f);
    x += 0x7fffu + ((x >> 16) & 1u);
    return (ushort)(x >> 16);
}
__device__ inline float bf2f(ushort u) {
    uint32_t x = ((uint32_t)u) << 16;
    return __builtin_bit_cast(float, x);
}
__device__ inline float u2f(uint u) { return __builtin_bit_cast(float, u); }
__device__ inline uint f2u(float f) { return __builtin_bit_cast(uint, f); }
__device__ inline float lo_bf(uint p) { return __builtin_bit_cast(float, p << 16); }
__device__ inline float hi_bf(uint p) { return __builtin_bit_cast(float, p & 0xffff0000u); }

__device__ inline void load_lds16(const void* g, void* l) {
    __builtin_amdgcn_global_load_lds(
        (const __attribute__((address_space(1))) void*)g,
        (__attribute__((address_space(3))) void*)l, 16, 0, 0);
}

// ---------------------------------------------------------------------------
// fp32 -> bf16 for the 3 weight matrices in one launch
// ---------------------------------------------------------------------------
__global__ __launch_bounds__(256) void f2bf3_kernel(
    const float* __restrict__ wa, const float* __restrict__ wb,
    const float* __restrict__ wc,
    ushort* __restrict__ oa, ushort* __restrict__ ob, ushort* __restrict__ oc)
{
    int i = (blockIdx.x * 256 + threadIdx.x) * 4;
    const int na = HF * DD, nb2 = 2 * HF * DD, nc3 = 2 * HF * DD + HF * HF;
    const float* src; ushort* dst; int o;
    if (i < na)       { src = wa; dst = oa; o = i; }
    else if (i < nb2) { src = wb; dst = ob; o = i - na; }
    else if (i < nc3) { src = wc; dst = oc; o = i - nb2; }
    else return;
    float4 v = *(const float4*)(src + o);
    ushort4 u;
    u.x = f2bf(v.x); u.y = f2bf(v.y); u.z = f2bf(v.z); u.w = f2bf(v.w);
    *(ushort4*)(dst + o) = u;
}

// ---------------------------------------------------------------------------
// FUSED: attn logits + dual projection GEMM. One 64-node tile per block.
// Pipelined 2-barrier step:
//   pre  : issue As(t) global_load_lds FIRST, then logit FMAs (overlap W L2
//          latency with VALU), barrier1.
//   post : prefetch feat(t+1), frag ds_reads + 16 MFMA, pack+ds_write
//          Bs[(t+1)&1] (double-buffered), barrier2.
// Logit arithmetic: identical expressions in identical k order as the
// verified build -> bit-identical outputs.
// ---------------------------------------------------------------------------
template<int K>
__global__ __launch_bounds__(256) void gemm_dual_attn(
    const ushort* __restrict__ W0,     // [128][K] bf16
    const ushort* __restrict__ W1,     // [128][K] bf16
    const float*  __restrict__ Xf,     // [NN][K] fp32 feat
    const float*  __restrict__ Was,    // [2][K] fp32
    const float*  __restrict__ Wad,    // [2][K] fp32
    const float*  __restrict__ bias1,  // [128]
    float* __restrict__ a_src, float* __restrict__ a_dst,
    ushort* __restrict__ out0, ushort* __restrict__ out1)
{
    __shared__ ushort As[2][128 * 32];   // 16 KB, per-step W slabs
    __shared__ ushort Bs[2][64 * 32];    // 8 KB, double-buffered B tile
    __shared__ float  wlds[4][K];        // 4 KB, attn vectors

    const int tid  = threadIdx.x;
    const int lane = tid & 63, wv = tid >> 6;
    const int wm = wv >> 1, wn = wv & 1;
    const int r = lane & 15, quad = lane >> 4;
    const int m0 = blockIdx.x * 64;

    // preload attn vectors: 4 x K floats, 1 float4 per thread
    {
        int vec = tid >> 6, e = (tid & 63) * 4;
        const float* src = (vec < 2) ? (Was + vec * K + e) : (Wad + (vec - 2) * K + e);
        *(float4*)&wlds[vec][e] = *(const float4*)src;
    }

    // thread -> (node = tid>>2, k-octet = (tid&3)*8) for B staging + logits
    const int node = tid >> 2;
    const int kq   = (tid & 3) * 8;
    int gm = m0 + node; gm = gm < NN ? gm : NN - 1;
    const float* frow = Xf + (size_t)gm * K;

    float p0 = 0.f, p1 = 0.f, p2 = 0.f, p3 = 0.f;
    f32x4 acc[2][4][2] = {};

    // prologue: load step-0 feat octets, stage Bs[0]
    float4 fa = *(const float4*)(frow + kq);
    float4 fb = *(const float4*)(frow + kq + 4);
    {
        uint q0 = ((uint)f2bf(fa.y) << 16) | f2bf(fa.x);
        uint q1 = ((uint)f2bf(fa.w) << 16) | f2bf(fa.z);
        uint q2 = ((uint)f2bf(fb.y) << 16) | f2bf(fb.x);
        uint q3 = ((uint)f2bf(fb.w) << 16) | f2bf(fb.z);
        *(uint4*)&Bs[0][node * 32 + kq] = make_uint4(q0, q1, q2, q3);
    }
    __syncthreads();   // wlds + Bs[0] ready

    const int NSTEP = K / 32;
    for (int s = 0; s < NSTEP; ++s) {
        const int k0 = s * 32;
        const int k  = k0 + kq;

        // --- pre phase: issue W staging FIRST, then logits overlap it ---
#pragma unroll
        for (int t = 0; t < 2; ++t) {
            int is  = wv + t * 4;
            int row = is * 16 + (lane >> 2);
            int ko  = k0 + (lane & 3) * 8;
            load_lds16(W0 + (size_t)row * K + ko, &As[0][is * 512]);
            load_lds16(W1 + (size_t)row * K + ko, &As[1][is * 512]);
        }
        {
            float4 wv0a = *(const float4*)&wlds[0][k];
            float4 wv0b = *(const float4*)&wlds[0][k + 4];
            float4 wv1a = *(const float4*)&wlds[1][k];
            float4 wv1b = *(const float4*)&wlds[1][k + 4];
            float4 wv2a = *(const float4*)&wlds[2][k];
            float4 wv2b = *(const float4*)&wlds[2][k + 4];
            float4 wv3a = *(const float4*)&wlds[3][k];
            float4 wv3b = *(const float4*)&wlds[3][k + 4];
            p0 += fa.x*wv0a.x + fa.y*wv0a.y + fa.z*wv0a.z + fa.w*wv0a.w
                + fb.x*wv0b.x + fb.y*wv0b.y + fb.z*wv0b.z + fb.w*wv0b.w;
            p1 += fa.x*wv1a.x + fa.y*wv1a.y + fa.z*wv1a.z + fa.w*wv1a.w
                + fb.x*wv1b.x + fb.y*wv1b.y + fb.z*wv1b.z + fb.w*wv1b.w;
            p2 += fa.x*wv2a.x + fa.y*wv2a.y + fa.z*wv2a.z + fa.w*wv2a.w
                + fb.x*wv2b.x + fb.y*wv2b.y + fb.z*wv2b.z + fb.w*wv2b.w;
            p3 += fa.x*wv3a.x + fa.y*wv3a.y + fa.z*wv3a.z + fa.w*wv3a.w
                + fb.x*wv3b.x + fb.y*wv3b.y + fb.z*wv3b.z + fb.w*wv3b.w;
        }
        __syncthreads();   // barrier1: As(s) drained; Bs[s&1] already staged

        // --- post phase: prefetch feat(t+1), MFMA on (As, Bs[s&1]),
        //     pack+write Bs[(s+1)&1] ---
        float4 fa_n, fb_n;
        if (s + 1 < NSTEP) {
            fa_n = *(const float4*)(frow + k0 + 32 + kq);
            fb_n = *(const float4*)(frow + k0 + 36 + kq);
        }

        bf16x8 a[2][4], b[2];
#pragma unroll
        for (int i = 0; i < 4; ++i) {
            a[0][i] = __builtin_bit_cast(bf16x8,
                      *(const f32x4*)&As[0][(wm * 64 + i * 16 + r) * 32 + quad * 8]);
            a[1][i] = __builtin_bit_cast(bf16x8,
                      *(const f32x4*)&As[1][(wm * 64 + i * 16 + r) * 32 + quad * 8]);
        }
#pragma unroll
        for (int j = 0; j < 2; ++j)
            b[j] = __builtin_bit_cast(bf16x8,
                   *(const f32x4*)&Bs[s & 1][(wn * 32 + j * 16 + r) * 32 + quad * 8]);
#pragma unroll
        for (int ss = 0; ss < 2; ++ss)
#pragma unroll
            for (int i = 0; i < 4; ++i)
#pragma unroll
                for (int j = 0; j < 2; ++j)
                    acc[ss][i][j] = __builtin_amdgcn_mfma_f32_16x16x32_bf16(
                        a[ss][i], b[j], acc[ss][i][j], 0, 0, 0);

        if (s + 1 < NSTEP) {
            uint q0 = ((uint)f2bf(fa_n.y) << 16) | f2bf(fa_n.x);
            uint q1 = ((uint)f2bf(fa_n.w) << 16) | f2bf(fa_n.z);
            uint q2 = ((uint)f2bf(fb_n.y) << 16) | f2bf(fb_n.x);
            uint q3 = ((uint)f2bf(fb_n.w) << 16) | f2bf(fb_n.z);
            *(uint4*)&Bs[(s + 1) & 1][node * 32 + kq] = make_uint4(q0, q1, q2, q3);
            fa = fa_n; fb = fb_n;
        }
        __syncthreads();   // barrier2: Bs[(s+1)&1] staged for next step
    }

    // fold the 4 k-octet threads of each node + store logits
    p0 += __shfl_xor(p0, 1); p0 += __shfl_xor(p0, 2);
    p1 += __shfl_xor(p1, 1); p1 += __shfl_xor(p1, 2);
    p2 += __shfl_xor(p2, 1); p2 += __shfl_xor(p2, 2);
    p3 += __shfl_xor(p3, 1); p3 += __shfl_xor(p3, 2);
    if ((tid & 3) == 0 && m0 + node < NN) {
        *(float2*)&a_src[(size_t)(m0 + node) * 2] = make_float2(p0, p1);
        *(float2*)&a_dst[(size_t)(m0 + node) * 2] = make_float2(p2, p3);
    }

#pragma unroll
    for (int s = 0; s < 2; ++s) {
        ushort* outp = s ? out1 : out0;
#pragma unroll
        for (int i = 0; i < 4; ++i) {
            int fbase = wm * 64 + i * 16 + quad * 4;
            float4 bv = make_float4(0.f, 0.f, 0.f, 0.f);
            if (s == 1) bv = *(const float4*)(bias1 + fbase);
#pragma unroll
            for (int j = 0; j < 2; ++j) {
                int node2 = m0 + wn * 32 + j * 16 + r;
                if (node2 >= NN) continue;
                f32x4 v = acc[s][i][j];
                v[0] += bv.x; v[1] += bv.y; v[2] += bv.z; v[3] += bv.w;
                ushort4 o;
                o.x = f2bf(v[0]); o.y = f2bf(v[1]); o.z = f2bf(v[2]); o.w = f2bf(v[3]);
                *(ushort4*)(outp + (size_t)node2 * HF + fbase) = o;
            }
        }
    }
}

// ---------------------------------------------------------------------------
// ngnn GEMM (K=128): fp32 out[node][f] = relu(acc+bias) + bf2f(resid)
// ---------------------------------------------------------------------------
template<int K>
__global__ __launch_bounds__(256) void mfma_gemm_ngnn(
    const ushort* __restrict__ Wb,
    const ushort* __restrict__ Xb,
    const float*  __restrict__ bias,
    const ushort* __restrict__ resid,
    float* __restrict__ outp)
{
    __shared__ ushort As[128 * 32];
    __shared__ ushort Bs[128 * 32];

    const int tid  = threadIdx.x;
    const int lane = tid & 63, wv = tid >> 6;
    const int wm = wv >> 1, wn = wv & 1;
    const int r = lane & 15, quad = lane >> 4;
    const int m0 = blockIdx.x * 128;

    f32x4 acc[4][4] = {};

    for (int k0 = 0; k0 < K; k0 += 32) {
#pragma unroll
        for (int t = 0; t < 2; ++t) {
            int is  = wv + t * 4;
            int row = is * 16 + (lane >> 2);
            int ko  = k0 + (lane & 3) * 8;
            load_lds16(Wb + (size_t)row * K + ko, &As[is * 512]);
            int gm = m0 + row; gm = gm < NN ? gm : NN - 1;
            load_lds16(Xb + (size_t)gm * K + ko, &Bs[is * 512]);
        }
        __syncthreads();
        bf16x8 a[4], b[4];
#pragma unroll
        for (int i = 0; i < 4; ++i) {
            a[i] = __builtin_bit_cast(bf16x8,
                   *(const f32x4*)&As[(wm * 64 + i * 16 + r) * 32 + quad * 8]);
            b[i] = __builtin_bit_cast(bf16x8,
                   *(const f32x4*)&Bs[(wn * 64 + i * 16 + r) * 32 + quad * 8]);
        }
#pragma unroll
        for (int i = 0; i < 4; ++i)
#pragma unroll
            for (int j = 0; j < 4; ++j)
                acc[i][j] = __builtin_amdgcn_mfma_f32_16x16x32_bf16(
                    a[i], b[j], acc[i][j], 0, 0, 0);
        __syncthreads();
    }

#pragma unroll
    for (int i = 0; i < 4; ++i) {
        int fbase = wm * 64 + i * 16 + quad * 4;
        float4 bv = *(const float4*)(bias + fbase);
#pragma unroll
        for (int j = 0; j < 4; ++j) {
            int node = m0 + wn * 64 + j * 16 + r;
            if (node >= NN) continue;
            f32x4 v = acc[i][j];
            ushort4 rs = *(const ushort4*)(resid + (size_t)node * HF + fbase);
            float4 o;
            o.x = fmaxf(v[0] + bv.x, 0.f) + bf2f(rs.x);
            o.y = fmaxf(v[1] + bv.y, 0.f) + bf2f(rs.y);
            o.z = fmaxf(v[2] + bv.z, 0.f) + bf2f(rs.z);
            o.w = fmaxf(v[3] + bv.w, 0.f) + bf2f(rs.w);
            *(float4*)(outp + (size_t)node * HF + fbase) = o;
        }
    }
}

// ---------------------------------------------------------------------------
// CSR degree histogram + scan
// ---------------------------------------------------------------------------
__global__ __launch_bounds__(256) void hist_kernel(
    const int* __restrict__ edge_dst, int* __restrict__ deg)
{
    int i = blockIdx.x * 256 + threadIdx.x;
    if (i < EE) atomicAdd(&deg[edge_dst[i]], 1);
}

#define SCAN_ELEMS 1024
__global__ __launch_bounds__(256) void scan1_kernel(
    const int* __restrict__ deg, int* __restrict__ offsets, int* __restrict__ blockSums)
{
    __shared__ int sd[256];
    int tid = threadIdx.x;
    int base = blockIdx.x * SCAN_ELEMS + tid * 4;
    int v[4];
#pragma unroll
    for (int c = 0; c < 4; ++c) v[c] = (base + c < NN) ? deg[base + c] : 0;
    int tsum = v[0] + v[1] + v[2] + v[3];
    sd[tid] = tsum;
    __syncthreads();
    for (int o = 1; o < 256; o <<= 1) {
        int x = (tid >= o) ? sd[tid - o] : 0;
        __syncthreads();
        sd[tid] += x;
        __syncthreads();
    }
    int excl = sd[tid] - tsum;
    int run = excl;
#pragma unroll
    for (int c = 0; c < 4; ++c) {
        if (base + c < NN) offsets[base + c] = run;
        run += v[c];
    }
    if (tid == 255) blockSums[blockIdx.x] = sd[255];
}

__global__ __launch_bounds__(128) void scan2_kernel(int* __restrict__ blockSums, int nb)
{
    __shared__ int sd[128];
    int tid = threadIdx.x;
    int tv = (tid < nb) ? blockSums[tid] : 0;
    sd[tid] = tv;
    __syncthreads();
    for (int o = 1; o < 128; o <<= 1) {
        int x = (tid >= o) ? sd[tid - o] : 0;
        __syncthreads();
        sd[tid] += x;
        __syncthreads();
    }
    if (tid < nb) blockSums[tid] = sd[tid] - tv;
}

// scan3 + bucket-cursor init fused
__global__ __launch_bounds__(256) void scan3_kernel(
    int* __restrict__ offsets, const int* __restrict__ blockSums,
    int* __restrict__ bcur)
{
    int tid = threadIdx.x;
    int base = blockIdx.x * SCAN_ELEMS + tid * 4;
    int add = blockSums[blockIdx.x];
#pragma unroll
    for (int c = 0; c < 4; ++c) {
        int idx = base + c;
        if (idx < NN) {
            int v = offsets[idx] + add;
            offsets[idx] = v;
            if ((idx & 511) == 0) bcur[idx >> 9] = v;
        }
    }
    if (blockIdx.x == 0 && tid == 0) offsets[NN] = EE;
}

// ---------------------------------------------------------------------------
// Phase 1: fused edge-score + coarse bucket scatter.
// ---------------------------------------------------------------------------
__global__ __launch_bounds__(P1_TPB) void bucket_scatter_kernel(
    const int* __restrict__ edge_src, const int* __restrict__ edge_dst,
    const float* __restrict__ feat_edge,
    const float* __restrict__ a_src, const float* __restrict__ a_dst,
    const float* __restrict__ Wae,
    int* __restrict__ bcur, uint4* __restrict__ staging)
{
    __shared__ uint4 rec[P1_EPB];      // 32 KB in-block sorted records
    __shared__ int cnt[256];
    __shared__ int scanv[256];         // exclusive bucket start within block
    __shared__ int cur[256];           // running cursor for LDS scatter
    __shared__ int basearr[256];       // global base per bucket
    __shared__ int wsum[4];

    const int tid = threadIdx.x;
    const int lane = tid & 63;
    const int b0 = blockIdx.x * P1_EPB;

    if (tid < 256) cnt[tid] = 0;
    __syncthreads();

    // Pass A: load (src,dst) once, histogram coarse buckets
    int sA[P1_ITER], dA[P1_ITER];
#pragma unroll
    for (int j = 0; j < P1_ITER; ++j) {
        int i = b0 + j * P1_TPB + tid;
        int s = 0, d = 0;
        if (i < EE) {
            s = edge_src[i];
            d = edge_dst[i];
            atomicAdd(&cnt[d >> 9], 1);
        }
        sA[j] = s; dA[j] = d;
    }
    __syncthreads();

    // 256-entry exclusive scan: wave-shuffle scan (waves 0-3) + tiny combine
    int c = (tid < 256) ? cnt[tid] : 0;
    int x = c;
#pragma unroll
    for (int o = 1; o < 64; o <<= 1) {
        int y = __shfl_up(x, o);
        if (lane >= o) x += y;
    }
    if (tid < 256 && lane == 63) wsum[tid >> 6] = x;
    __syncthreads();
    if (tid < 256) {
        int w4 = tid >> 6;
        int add = 0;
        if (w4 > 0) add += wsum[0];
        if (w4 > 1) add += wsum[1];
        if (w4 > 2) add += wsum[2];
        int excl = x - c + add;
        cur[tid]   = excl;
        scanv[tid] = excl;
        if (tid < NBUCK) basearr[tid] = c ? atomicAdd(&bcur[tid], c) : 0;
    }
    __syncthreads();

    float4 w00 = ((const float4*)Wae)[0], w01 = ((const float4*)Wae)[1];
    float4 w10 = ((const float4*)Wae)[2], w11 = ((const float4*)Wae)[3];

    // Pass B prefetch: issue ALL global loads before any compute
    float4 e0v[P1_ITER], e1v[P1_ITER];
    float2 asv[P1_ITER], adv[P1_ITER];
#pragma unroll
    for (int j = 0; j < P1_ITER; ++j) {
        int i = b0 + j * P1_TPB + tid;
        if (i >= EE) continue;
        e0v[j] = ((const float4*)feat_edge)[i * 2 + 0];
        e1v[j] = ((const float4*)feat_edge)[i * 2 + 1];
        asv[j] = ((const float2*)a_src)[sA[j]];
        adv[j] = ((const float2*)a_dst)[dA[j]];
    }

    // Pass B compute: scores, scatter records into LDS at sorted position
#pragma unroll
    for (int j = 0; j < P1_ITER; ++j) {
        int i = b0 + j * P1_TPB + tid;
        if (i >= EE) continue;
        int s = sA[j], d = dA[j];
        float4 e0 = e0v[j], e1 = e1v[j];
        float ae0 = e0.x*w00.x + e0.y*w00.y + e0.z*w00.z + e0.w*w00.w
                  + e1.x*w01.x + e1.y*w01.y + e1.z*w01.z + e1.w*w01.w;
        float ae1 = e0.x*w10.x + e0.y*w10.y + e0.z*w10.z + e0.w*w10.w
                  + e1.x*w11.x + e1.y*w11.y + e1.z*w11.z + e1.w*w11.w;
        float v0 = asv[j].x + adv[j].x + ae0;
        float v1 = asv[j].y + adv[j].y + ae1;
        v0 = (v0 >= 0.f) ? v0 : NEG_SLOPE * v0;
        v1 = (v1 >= 0.f) ? v1 : NEG_SLOPE * v1;
        int bk = d >> 9;
        int pos = atomicAdd(&cur[bk], 1);
        rec[pos] = make_uint4((uint)s, (uint)d, f2u(v0), f2u(v1));
    }
    __syncthreads();

    // Pass C: linear write-out; consecutive lanes -> consecutive global addrs
    const int tot = (EE - b0 < P1_EPB) ? (EE - b0) : P1_EPB;
    for (int idx = tid; idx < tot; idx += P1_TPB) {
        uint4 r = rec[idx];
        int bk = (int)(r.y >> 9);
        staging[basearr[bk] + (idx - scanv[bk])] = r;
    }
}

// ---------------------------------------------------------------------------
// Phase 2: fine scatter within bucket (LDS cursors; L2-absorbed writes).
// ---------------------------------------------------------------------------
__global__ __launch_bounds__(1024) void fine_scatter_kernel(
    const int* __restrict__ offsets,
    const uint4* __restrict__ staging, uint4* __restrict__ pairs)
{
    __shared__ int cur[512];
    const int tid = threadIdx.x;
    const int nb0 = blockIdx.x * 512;
    const int ncnt = (NN - nb0 < 512) ? (NN - nb0) : 512;
    for (int i = tid; i < ncnt; i += 1024) cur[i] = offsets[nb0 + i];
    __syncthreads();
    const int lo = offsets[nb0];
    const int hi = offsets[nb0 + ncnt];
    for (int j = lo + tid; j < hi; j += 1024) {
        uint4 it = staging[j];
        int n = (int)it.y - nb0;
        int pos = atomicAdd(&cur[n], 1);
        pairs[pos] = it;
    }
}

// ---------------------------------------------------------------------------
// Fused edge-softmax + aggregation. One wave per dst node.
// ---------------------------------------------------------------------------
__global__ __launch_bounds__(256) void aggregate_fused(
    const int* __restrict__ offsets,
    const uint4* __restrict__ pairs,
    const ushort* __restrict__ hsrc,
    ushort* __restrict__ agg)
{
    __shared__ uint4 stash[4][64];
    const int wave = threadIdx.x >> 6, lane = threadIdx.x & 63;
    const int node = blockIdx.x * 4 + wave;
    if (node >= NN) return;
    const int off = offsets[node], end = offsets[node + 1];
    const int n = end - off;
    const int q4 = lane & 15;         // uint4 column within the 256 B row
    const int grp = lane >> 4;        // edge group 0..3
    const int h0 = (q4 < 8);          // features 8*q4..8*q4+7 -> head0 iff q4<8
    uint4* agg4 = (uint4*)agg;
    if (n <= 0) {
        if (grp == 0) agg4[(size_t)node * 16 + q4] = make_uint4(0u, 0u, 0u, 0u);
        return;
    }
    const uint4* hp4 = (const uint4*)hsrc;

    float a0 = 0.f, a1 = 0.f, a2 = 0.f, a3 = 0.f;
    float a4 = 0.f, a5 = 0.f, a6 = 0.f, a7 = 0.f;
    float z0 = 0.f, z1 = 0.f;

    if (n <= 64) {
        uint4 pr = (lane < n) ? pairs[off + lane]
                              : make_uint4(0u, 0u, 0xff800000u, 0xff800000u);
        float m0 = u2f(pr.z), m1 = u2f(pr.w);
#pragma unroll
        for (int o = 32; o > 0; o >>= 1) {
            m0 = fmaxf(m0, __shfl_xor(m0, o));
            m1 = fmaxf(m1, __shfl_xor(m1, o));
        }
        float ex0 = (lane < n) ? __expf(u2f(pr.z) - m0) : 0.f;
        float ex1 = (lane < n) ? __expf(u2f(pr.w) - m1) : 0.f;
        z0 = ex0; z1 = ex1;
        stash[wave][lane] = make_uint4(pr.x, f2u(ex0), f2u(ex1), 0u);
        __builtin_amdgcn_wave_barrier();
        const int nt = (n + 3) >> 2;
#pragma unroll 4
        for (int t = 0; t < nt; ++t) {
            uint4 st = stash[wave][t * 4 + grp];
            float w = h0 ? u2f(st.y) : u2f(st.z);
            uint4 p = hp4[(size_t)st.x * 16 + q4];
            a0 = fmaf(w, lo_bf(p.x), a0); a1 = fmaf(w, hi_bf(p.x), a1);
            a2 = fmaf(w, lo_bf(p.y), a2); a3 = fmaf(w, hi_bf(p.y), a3);
            a4 = fmaf(w, lo_bf(p.z), a4); a5 = fmaf(w, hi_bf(p.z), a5);
            a6 = fmaf(w, lo_bf(p.w), a6); a7 = fmaf(w, hi_bf(p.w), a7);
        }
    } else {
        float m0 = -INFINITY, m1 = -INFINITY;
        for (int c0 = 0; c0 < n; c0 += 64) {
            if (c0 + lane < n) {
                uint4 pr = pairs[off + c0 + lane];
                m0 = fmaxf(m0, u2f(pr.z));
                m1 = fmaxf(m1, u2f(pr.w));
            }
        }
#pragma unroll
        for (int o = 32; o > 0; o >>= 1) {
            m0 = fmaxf(m0, __shfl_xor(m0, o));
            m1 = fmaxf(m1, __shfl_xor(m1, o));
        }
        for (int c0 = 0; c0 < n; c0 += 64) {
            int cn = n - c0; if (cn > 64) cn = 64;
            uint srcv = 0; float ex0 = 0.f, ex1 = 0.f;
            if (lane < cn) {
                uint4 pr = pairs[off + c0 + lane];
                srcv = pr.x;
                ex0 = __expf(u2f(pr.z) - m0);
                ex1 = __expf(u2f(pr.w) - m1);
                z0 += ex0; z1 += ex1;
            }
            __builtin_amdgcn_wave_barrier();
            stash[wave][lane] = make_uint4(srcv, f2u(ex0), f2u(ex1), 0u);
            __builtin_amdgcn_wave_barrier();
            const int nt = (cn + 3) >> 2;
#pragma unroll 4
            for (int t = 0; t < nt; ++t) {
                uint4 st = stash[wave][t * 4 + grp];
                float w = h0 ? u2f(st.y) : u2f(st.z);
                uint4 p = hp4[(size_t)st.x * 16 + q4];
                a0 = fmaf(w, lo_bf(p.x), a0); a1 = fmaf(w, hi_bf(p.x), a1);
                a2 = fmaf(w, lo_bf(p.y), a2); a3 = fmaf(w, hi_bf(p.y), a3);
                a4 = fmaf(w, lo_bf(p.z), a4); a5 = fmaf(w, hi_bf(p.z), a5);
                a6 = fmaf(w, lo_bf(p.w), a6); a7 = fmaf(w, hi_bf(p.w), a7);
            }
            __builtin_amdgcn_wave_barrier();
        }
    }

    // fold the 4 edge-groups (lanes q4, q4+16, q4+32, q4+48) + z reduce
#pragma unroll
    for (int o = 32; o >= 16; o >>= 1) {
        a0 += __shfl_xor(a0, o); a1 += __shfl_xor(a1, o);
        a2 += __shfl_xor(a2, o); a3 += __shfl_xor(a3, o);
        a4 += __shfl_xor(a4, o); a5 += __shfl_xor(a5, o);
        a6 += __shfl_xor(a6, o); a7 += __shfl_xor(a7, o);
    }
#pragma unroll
    for (int o = 32; o > 0; o >>= 1) {
        z0 += __shfl_xor(z0, o);
        z1 += __shfl_xor(z1, o);
    }
    float zi = h0 ? ((z0 > 0.f) ? 1.f / z0 : 0.f)
                  : ((z1 > 0.f) ? 1.f / z1 : 0.f);
    if (grp == 0) {
        uint4 o4;
        o4.x = ((uint)f2bf(a1 * zi) << 16) | (uint)f2bf(a0 * zi);
        o4.y = ((uint)f2bf(a3 * zi) << 16) | (uint)f2bf(a2 * zi);
        o4.z = ((uint)f2bf(a5 * zi) << 16) | (uint)f2bf(a4 * zi);
        o4.w = ((uint)f2bf(a7 * zi) << 16) | (uint)f2bf(a6 * zi);
        agg4[(size_t)node * 16 + q4] = o4;
    }
}

// ---------------------------------------------------------------------------
extern "C" void kernel_launch(void* const* d_in, const int* in_sizes, int n_in,
                              void* d_out, int out_size, void* d_ws, size_t ws_size,
                              hipStream_t stream) {
    (void)in_sizes; (void)n_in; (void)out_size; (void)ws_size;
    const float* feat_src  = (const float*)d_in[0];
    const float* feat_edge = (const float*)d_in[1];
    const int*   edge_src  = (const int*)d_in[2];
    const int*   edge_dst  = (const int*)d_in[3];
    const float* W_src     = (const float*)d_in[4];
    const float* W_dst     = (const float*)d_in[5];
    const float* b_dst     = (const float*)d_in[6];
    const float* W_attn_src  = (const float*)d_in[7];
    const float* W_attn_dst  = (const float*)d_in[8];
    const float* W_attn_edge = (const float*)d_in[9];
    const float* W_ngnn    = (const float*)d_in[10];
    const float* b_ngnn    = (const float*)d_in[11];
    float* out = (float*)d_out;

    char* base = (char*)d_ws;
    size_t off = 0;
    auto take = [&](size_t bytes) -> void* {
        void* p = base + off;
        off = (off + bytes + 511) & ~(size_t)511;
        return p;
    };
    ushort* h_src_bf = (ushort*)take((size_t)NN * HF * 2);    // 25.6 MB
    ushort* h_dst_bf = (ushort*)take((size_t)NN * HF * 2);    // 25.6 MB
    ushort* agg_bf   = (ushort*)take((size_t)NN * HF * 2);    // 25.6 MB
    uint4*  staging  = (uint4*)take((size_t)EE * 16);         // 25.6 MB
    uint4*  pairs    = (uint4*)take((size_t)EE * 16);         // 25.6 MB
    float*  a_src_b  = (float*)take((size_t)NN * 2 * 4);
    float*  a_dst_b  = (float*)take((size_t)NN * 2 * 4);
    int*    deg      = (int*)take((size_t)NN * 4);
    int*    offsets  = (int*)take((size_t)(NN + 1) * 4);
    int*    bcur     = (int*)take((size_t)NBUCK * 4);
    int*    blockSums= (int*)take(512);
    ushort* Wsrc_bf  = (ushort*)take((size_t)HF * DD * 2);
    ushort* Wdst_bf  = (ushort*)take((size_t)HF * DD * 2);
    ushort* Wngnn_bf = (ushort*)take((size_t)HF * HF * 2);

    const int NB_SCAN = (NN + SCAN_ELEMS - 1) / SCAN_ELEMS;   // 98
    const int GB_E  = (EE + 255) / 256;                       // 6250
    const int GB_M  = (NN + 127) / 128;                       // 782
    const int GB_M64= (NN + 63) / 64;                         // 1563
    const int GB_N4 = (NN + 3) / 4;                           // 25000
    const int GB_P1 = (EE + P1_EPB - 1) / P1_EPB;             // 782
    const int W3_N  = (2 * HF * DD + HF * HF) / 4;            // 20480
    const int GB_W3 = (W3_N + 255) / 256;                     // 80

    // CSR offsets (+ bucket cursor init fused into scan3)
    hipMemsetAsync(deg, 0, (size_t)NN * 4, stream);
    hipLaunchKernelGGL(hist_kernel, dim3(GB_E), dim3(256), 0, stream, edge_dst, deg);
    hipLaunchKernelGGL(scan1_kernel, dim3(NB_SCAN), dim3(256), 0, stream, deg, offsets, blockSums);
    hipLaunchKernelGGL(scan2_kernel, dim3(1), dim3(128), 0, stream, blockSums, NB_SCAN);
    hipLaunchKernelGGL(scan3_kernel, dim3(NB_SCAN), dim3(256), 0, stream, offsets, blockSums, bcur);

    // weight conversions (single launch)
    hipLaunchKernelGGL(f2bf3_kernel, dim3(GB_W3), dim3(256), 0, stream,
                       W_src, W_dst, W_ngnn, Wsrc_bf, Wdst_bf, Wngnn_bf);

    // FUSED attn logits + dual projection GEMM (feat fp32 read exactly once)
    hipLaunchKernelGGL((gemm_dual_attn<DD>), dim3(GB_M64), dim3(256), 0, stream,
                       Wsrc_bf, Wdst_bf, feat_src, W_attn_src, W_attn_dst, b_dst,
                       a_src_b, a_dst_b, h_src_bf, h_dst_bf);

    // edge scores + 2-phase counting sort into CSR order
    hipLaunchKernelGGL(bucket_scatter_kernel, dim3(GB_P1), dim3(P1_TPB), 0, stream,
                       edge_src, edge_dst, feat_edge, a_src_b, a_dst_b, W_attn_edge,
                       bcur, staging);
    hipLaunchKernelGGL(fine_scatter_kernel, dim3(NBUCK), dim3(1024), 0, stream,
                       offsets, staging, pairs);

    // fused softmax + aggregation
    hipLaunchKernelGGL(aggregate_fused, dim3(GB_N4), dim3(256), 0, stream,
                       offsets, pairs, h_src_bf, agg_bf);

    // ngnn + relu + residual -> fp32 out
    hipLaunchKernelGGL(mfma_gemm_ngnn<HF>, dim3(GB_M), dim3(256), 0, stream,
                       Wngnn_bf, agg_bf, b_ngnn, h_dst_bf, out);
}